// Round 1
// baseline (1593.017 us; speedup 1.0000x reference)
//
#include <hip/hip_runtime.h>
#include <cstdint>
#include <cstddef>
#include <math.h>

#define B_ 2
#define T_ 2048
#define D_ 1024
#define M_ (B_*T_)   // 4096 tokens

// ---------------- stats: mean + std(ddof=1) over t, per (b,d) ----------------
__global__ void stats_partial(const float* __restrict__ x,
                              float* __restrict__ part, float* __restrict__ part2) {
    int d  = blockIdx.x * 256 + threadIdx.x;   // 0..1023
    int tc = blockIdx.y;                        // 0..15 (chunk of 128 t)
    int b  = blockIdx.z;
    const float* p = x + (size_t)b * T_ * D_ + (size_t)tc * 128 * D_ + d;
    float s = 0.f, s2 = 0.f;
    for (int t = 0; t < 128; ++t) {
        float v = p[(size_t)t * D_];
        s += v; s2 += v * v;
    }
    part [(b * 16 + tc) * D_ + d] = s;
    part2[(b * 16 + tc) * D_ + d] = s2;
}

__global__ void stats_final(const float* __restrict__ part, const float* __restrict__ part2,
                            float* __restrict__ ms) {
    int idx = blockIdx.x * 256 + threadIdx.x;  // b*D
    if (idx >= B_ * D_) return;
    int b = idx / D_, d = idx % D_;
    float s = 0.f, s2 = 0.f;
    for (int i = 0; i < 16; ++i) {
        s  += part [(b * 16 + i) * D_ + d];
        s2 += part2[(b * 16 + i) * D_ + d];
    }
    float mean = s / (float)T_;
    float var  = (s2 - (float)T_ * mean * mean) / (float)(T_ - 1);
    ms[idx] = mean + sqrtf(fmaxf(var, 0.f));
}

// ---------------- selector MLP + softmax -> probs[b,t,3] ----------------
__global__ void selector_kernel(const float* __restrict__ x, const float* __restrict__ ms,
                                const float* __restrict__ w1, const float* __restrict__ b1,
                                const float* __restrict__ w2, const float* __restrict__ b2,
                                const float* __restrict__ w3, const float* __restrict__ b3,
                                float* __restrict__ probs) {
    __shared__ float xs[D_];
    __shared__ float h1[64];
    __shared__ float h2s[64];
    __shared__ float lg[3];
    int bt = blockIdx.x;          // b*T + t
    int b  = bt / T_;
    int t  = bt % T_;
    int j  = threadIdx.x;         // 0..63
    float pos = 0.1f * (float)t / (float)T_;
    for (int d = j; d < D_; d += 64)
        xs[d] = x[(size_t)bt * D_ + d] + ms[b * D_ + d] + pos;
    __syncthreads();
    float acc = b1[j];
    for (int d = 0; d < D_; ++d) acc = fmaf(xs[d], w1[j * D_ + d], acc);
    h1[j] = fmaxf(acc, 0.f);
    __syncthreads();
    float acc2 = b2[j];
    for (int d = 0; d < 64; ++d) acc2 = fmaf(h1[d], w2[j * 64 + d], acc2);
    h2s[j] = fmaxf(acc2, 0.f);
    __syncthreads();
    if (j < 3) {
        float acc3 = b3[j];
        for (int d = 0; d < 64; ++d) acc3 = fmaf(h2s[d], w3[j * 64 + d], acc3);
        lg[j] = acc3;
    }
    __syncthreads();
    if (j == 0) {
        float m = fmaxf(lg[0], fmaxf(lg[1], lg[2]));
        float e0 = expf(lg[0] - m), e1 = expf(lg[1] - m), e2 = expf(lg[2] - m);
        float inv = 1.f / (e0 + e1 + e2);
        probs[(size_t)bt * 3 + 0] = e0 * inv;
        probs[(size_t)bt * 3 + 1] = e1 * inv;
        probs[(size_t)bt * 3 + 2] = e2 * inv;
    }
}

// ---------------- generic C[M,N] = A[M,K] * Bw[N,K]^T (fp32, 64x64 tile) ----------------
__global__ __launch_bounds__(256) void gemm_xwT(const float* __restrict__ A,
                                                const float* __restrict__ Bw,
                                                float* __restrict__ C,
                                                int N, int K, int ldc) {
    __shared__ float As[16][68];
    __shared__ float Bs[16][68];
    int tid = threadIdx.x;
    int bm = blockIdx.x * 64;
    int bn = blockIdx.y * 64;
    int tx = tid & 15, ty = tid >> 4;
    int lr = tid >> 2;          // 0..63
    int lk = (tid & 3) * 4;     // 0,4,8,12
    float c[4][4] = {};
    const float* ap = A + (size_t)(bm + lr) * K + lk;
    int nrow = bn + lr;
    const float* bp = Bw + (size_t)nrow * K + lk;
    bool bok = (nrow < N);
    for (int k0 = 0; k0 < K; k0 += 16) {
        float4 va = *(const float4*)(ap + k0);
        As[lk + 0][lr] = va.x; As[lk + 1][lr] = va.y;
        As[lk + 2][lr] = va.z; As[lk + 3][lr] = va.w;
        float4 vb = bok ? *(const float4*)(bp + k0) : make_float4(0.f, 0.f, 0.f, 0.f);
        Bs[lk + 0][lr] = vb.x; Bs[lk + 1][lr] = vb.y;
        Bs[lk + 2][lr] = vb.z; Bs[lk + 3][lr] = vb.w;
        __syncthreads();
#pragma unroll
        for (int kk = 0; kk < 16; ++kk) {
            float4 a = *(const float4*)&As[kk][ty * 4];
            float4 b = *(const float4*)&Bs[kk][tx * 4];
            c[0][0] += a.x * b.x; c[0][1] += a.x * b.y; c[0][2] += a.x * b.z; c[0][3] += a.x * b.w;
            c[1][0] += a.y * b.x; c[1][1] += a.y * b.y; c[1][2] += a.y * b.z; c[1][3] += a.y * b.w;
            c[2][0] += a.z * b.x; c[2][1] += a.z * b.y; c[2][2] += a.z * b.z; c[2][3] += a.z * b.w;
            c[3][0] += a.w * b.x; c[3][1] += a.w * b.y; c[3][2] += a.w * b.z; c[3][3] += a.w * b.w;
        }
        __syncthreads();
    }
#pragma unroll
    for (int rr = 0; rr < 4; ++rr) {
        int m = bm + ty * 4 + rr;
        int n0 = bn + tx * 4;
#pragma unroll
        for (int cc = 0; cc < 4; ++cc)
            if (n0 + cc < N) C[(size_t)m * ldc + n0 + cc] = c[rr][cc];
    }
}

// ---------------- fused relu-attention score kernel ----------------
// out[b,t,s] = sum_cfg probs[b,t,cfg] * sum_h relu(q_cfg[b,t,h,:].k_cfg[b,s,:]) * w_cfg[b,t,h]
__global__ __launch_bounds__(256) void score_kernel(
    const float* __restrict__ Q0, const float* __restrict__ Q1, const float* __restrict__ Q2,
    const float* __restrict__ K0, const float* __restrict__ K1c, const float* __restrict__ K2c,
    const float* __restrict__ WC, const float* __restrict__ PR, float* __restrict__ out) {
    __shared__ float Qs[32][68];
    __shared__ float Ks[32][68];
    __shared__ float wp[64][28];
    int tid = threadIdx.x;
    int b  = blockIdx.z;
    int t0 = blockIdx.y * 64;
    int s0 = blockIdx.x * 64;
    // per-(row, head) weight = w * prob
    for (int idx = tid; idx < 64 * 28; idx += 256) {
        int m = idx / 28, g = idx % 28;
        int cfg = (g < 4) ? 0 : (g < 12 ? 1 : 2);
        size_t bt = (size_t)(b * T_ + t0 + m);
        wp[m][g] = WC[bt * 28 + g] * PR[bt * 3 + cfg];
    }
    int tx = tid & 15, ty = tid >> 4;
    float c[4][4] = {};
    __syncthreads();

    const float* qb[3] = {Q0, Q1, Q2};
    const float* kb[3] = {K0, K1c, K2c};
    const int dims[3] = {32, 64, 128};
    const int nh[3]   = {4, 8, 16};
    const int qld[3]  = {128, 512, 2048};

    int g = 0;
    for (int cfg = 0; cfg < 3; ++cfg) {
        const int dcfg = dims[cfg];
        const int ldq  = qld[cfg];
        const float* Qp = qb[cfg] + (size_t)(b * T_ + t0) * ldq;
        const float* Kp = kb[cfg] + (size_t)(b * T_ + s0) * dcfg;
        for (int h = 0; h < nh[cfg]; ++h, ++g) {
            int hoff = h * dcfg;
            float r[4][4] = {};
            for (int d0 = 0; d0 < dcfg; d0 += 32) {
                // stage 64 rows x 32 cols of Q and K (transposed into LDS)
#pragma unroll
                for (int p = 0; p < 2; ++p) {
                    int fi  = tid + p * 256;
                    int row = fi >> 3;
                    int col = (fi & 7) * 4;
                    float4 vq = *(const float4*)(Qp + (size_t)row * ldq + hoff + d0 + col);
                    Qs[col + 0][row] = vq.x; Qs[col + 1][row] = vq.y;
                    Qs[col + 2][row] = vq.z; Qs[col + 3][row] = vq.w;
                    float4 vk = *(const float4*)(Kp + (size_t)row * dcfg + d0 + col);
                    Ks[col + 0][row] = vk.x; Ks[col + 1][row] = vk.y;
                    Ks[col + 2][row] = vk.z; Ks[col + 3][row] = vk.w;
                }
                __syncthreads();
#pragma unroll
                for (int kk = 0; kk < 32; ++kk) {
                    float4 a  = *(const float4*)&Qs[kk][ty * 4];
                    float4 bb = *(const float4*)&Ks[kk][tx * 4];
                    r[0][0] += a.x * bb.x; r[0][1] += a.x * bb.y; r[0][2] += a.x * bb.z; r[0][3] += a.x * bb.w;
                    r[1][0] += a.y * bb.x; r[1][1] += a.y * bb.y; r[1][2] += a.y * bb.z; r[1][3] += a.y * bb.w;
                    r[2][0] += a.z * bb.x; r[2][1] += a.z * bb.y; r[2][2] += a.z * bb.z; r[2][3] += a.z * bb.w;
                    r[3][0] += a.w * bb.x; r[3][1] += a.w * bb.y; r[3][2] += a.w * bb.z; r[3][3] += a.w * bb.w;
                }
                __syncthreads();
            }
#pragma unroll
            for (int rr = 0; rr < 4; ++rr) {
                float wg = wp[ty * 4 + rr][g];
#pragma unroll
                for (int cc = 0; cc < 4; ++cc)
                    c[rr][cc] += fmaxf(r[rr][cc], 0.f) * wg;
            }
        }
    }
#pragma unroll
    for (int rr = 0; rr < 4; ++rr) {
        float4 v = make_float4(c[rr][0], c[rr][1], c[rr][2], c[rr][3]);
        *(float4*)(out + ((size_t)(b * T_) + t0 + ty * 4 + rr) * T_ + s0 + tx * 4) = v;
    }
}

extern "C" void kernel_launch(void* const* d_in, const int* in_sizes, int n_in,
                              void* d_out, int out_size, void* d_ws, size_t ws_size,
                              hipStream_t stream) {
    const float* x   = (const float*)d_in[0];
    const float* w1  = (const float*)d_in[1];
    const float* b1  = (const float*)d_in[2];
    const float* w2  = (const float*)d_in[3];
    const float* b2  = (const float*)d_in[4];
    const float* w3  = (const float*)d_in[5];
    const float* b3  = (const float*)d_in[6];
    const float* qw0 = (const float*)d_in[7];
    const float* kw0 = (const float*)d_in[8];
    const float* ww0 = (const float*)d_in[9];
    const float* qw1 = (const float*)d_in[10];
    const float* kw1 = (const float*)d_in[11];
    const float* ww1 = (const float*)d_in[12];
    const float* qw2 = (const float*)d_in[13];
    const float* kw2 = (const float*)d_in[14];
    const float* ww2 = (const float*)d_in[15];
    float* out = (float*)d_out;
    float* ws  = (float*)d_ws;

    size_t off = 0;
    float* MS  = ws + off; off += (size_t)B_ * D_;        // mean+std per (b,d)
    float* PR  = ws + off; off += (size_t)B_ * T_ * 3;    // softmax probs
    float* WC  = ws + off; off += (size_t)B_ * T_ * 28;   // all w projections (4+8+16)
    float* Q0  = ws + off; off += (size_t)B_ * T_ * 128;
    float* Q1  = ws + off; off += (size_t)B_ * T_ * 512;
    float* Q2  = ws + off; off += (size_t)B_ * T_ * 2048;
    float* K0  = ws + off; off += (size_t)B_ * T_ * 32;
    float* K1c = ws + off; off += (size_t)B_ * T_ * 64;
    float* K2c = ws + off; off += (size_t)B_ * T_ * 128;
    float* PA  = ws + off; off += (size_t)B_ * 16 * D_;
    float* PA2 = ws + off; off += (size_t)B_ * 16 * D_;
    // total ~48.5 MB of workspace

    stats_partial<<<dim3(D_ / 256, 16, B_), 256, 0, stream>>>(x, PA, PA2);
    stats_final<<<dim3((B_ * D_ + 255) / 256), 256, 0, stream>>>(PA, PA2, MS);
    selector_kernel<<<dim3(B_ * T_), 64, 0, stream>>>(x, MS, w1, b1, w2, b2, w3, b3, PR);

    auto launch_gemm = [&](const float* Bw, float* C, int N, int ldc) {
        gemm_xwT<<<dim3(M_ / 64, (N + 63) / 64), 256, 0, stream>>>(x, Bw, C, N, D_, ldc);
    };
    launch_gemm(qw0, Q0, 128, 128);
    launch_gemm(kw0, K0, 32, 32);
    launch_gemm(ww0, WC + 0, 4, 28);
    launch_gemm(qw1, Q1, 512, 512);
    launch_gemm(kw1, K1c, 64, 64);
    launch_gemm(ww1, WC + 4, 8, 28);
    launch_gemm(qw2, Q2, 2048, 2048);
    launch_gemm(kw2, K2c, 128, 128);
    launch_gemm(ww2, WC + 12, 16, 28);

    score_kernel<<<dim3(T_ / 64, T_ / 64, B_), 256, 0, stream>>>(
        Q0, Q1, Q2, K0, K1c, K2c, WC, PR, out);
}

// Round 2
// 430.628 us; speedup vs baseline: 3.6993x; 3.6993x over previous
//
#include <hip/hip_runtime.h>
#include <cstdint>
#include <cstddef>
#include <math.h>

#define B_ 2
#define T_ 2048
#define D_ 1024
#define M_ (B_*T_)

// column layout of P (= row layout of Wsplit), all offsets multiples of 8
#define QO0 0
#define KO0 128
#define WO0 160
// pad 164..167 (zero)
#define QO1 168
#define KO1 680
#define WO1 744
#define QO2 752
#define KO2 2800
#define WO2 2928
#define SELO 2944
// zero pad 3008..3071
#define LDN 3072

typedef float f32x16 __attribute__((ext_vector_type(16)));
typedef short bf16x8 __attribute__((ext_vector_type(8)));
typedef unsigned short u16;

__device__ __forceinline__ u16 f2bf(float f) {
    unsigned int u = __float_as_uint(f);
    unsigned int r = (u + 0x7fffu + ((u >> 16) & 1u)) >> 16;   // RNE
    return (u16)r;
}
__device__ __forceinline__ float bf2f(u16 b) {
    return __uint_as_float(((unsigned int)b) << 16);
}

// async global->LDS, 16B per lane, dest = uniform base + lane*16
__device__ __forceinline__ void gload16(const void* g, void* l) {
    __builtin_amdgcn_global_load_lds(
        (const __attribute__((address_space(1))) unsigned int*)g,
        (__attribute__((address_space(3))) unsigned int*)l,
        16, 0, 0);
}

// ---------------- stats: mean + std(ddof=1) over t, per (b,d) ----------------
__global__ void stats_partial(const float* __restrict__ x,
                              float* __restrict__ part, float* __restrict__ part2) {
    int d  = blockIdx.x * 256 + threadIdx.x;
    int tc = blockIdx.y;
    int b  = blockIdx.z;
    const float* p = x + (size_t)b * T_ * D_ + (size_t)tc * 128 * D_ + d;
    float s = 0.f, s2 = 0.f;
    for (int t = 0; t < 128; ++t) {
        float v = p[(size_t)t * D_];
        s += v; s2 += v * v;
    }
    part [(b * 16 + tc) * D_ + d] = s;
    part2[(b * 16 + tc) * D_ + d] = s2;
}

__global__ void stats_final(const float* __restrict__ part, const float* __restrict__ part2,
                            float* __restrict__ ms) {
    int idx = blockIdx.x * 256 + threadIdx.x;
    if (idx >= B_ * D_) return;
    int b = idx / D_, d = idx % D_;
    float s = 0.f, s2 = 0.f;
    for (int i = 0; i < 16; ++i) {
        s  += part [(b * 16 + i) * D_ + d];
        s2 += part2[(b * 16 + i) * D_ + d];
    }
    float mean = s / (float)T_;
    float var  = (s2 - (float)T_ * mean * mean) / (float)(T_ - 1);
    ms[idx] = mean + sqrtf(fmaxf(var, 0.f));
}

// msd[b][j] = ms[b,:] . w1[j,:] ;  s1[j] = sum_d w1[j][d]
__global__ void msdot(const float* __restrict__ ms, const float* __restrict__ w1,
                      float* __restrict__ msd, float* __restrict__ s1) {
    int b = blockIdx.x, j = threadIdx.x;
    const float* wr = w1 + (size_t)j * D_;
    const float* mr = ms + (size_t)b * D_;
    float am = 0.f, as = 0.f;
    for (int d4 = 0; d4 < D_ / 4; ++d4) {
        float4 w = *(const float4*)(wr + d4 * 4);
        float4 m = *(const float4*)(mr + d4 * 4);
        am += w.x * m.x + w.y * m.y + w.z * m.z + w.w * m.w;
        as += w.x + w.y + w.z + w.w;
    }
    msd[b * 64 + j] = am;
    if (b == 0) s1[j] = as;
}

// ---------------- weight concat + bf16 hi/lo split: Wsplit[3072][1024] ----------------
__global__ void split_w(const float* __restrict__ qw0, const float* __restrict__ kw0,
                        const float* __restrict__ ww0, const float* __restrict__ qw1,
                        const float* __restrict__ kw1, const float* __restrict__ ww1,
                        const float* __restrict__ qw2, const float* __restrict__ kw2,
                        const float* __restrict__ ww2, const float* __restrict__ w1s,
                        u16* __restrict__ Wh, u16* __restrict__ Wl) {
    int row = blockIdx.x;           // one row per block (256 thr * 4 el)
    int col = threadIdx.x * 4;
    const float* src = nullptr;
    if      (row < 128)  src = qw0 + (size_t)row * D_;
    else if (row < 160)  src = kw0 + (size_t)(row - 128) * D_;
    else if (row < 164)  src = ww0 + (size_t)(row - 160) * D_;
    else if (row < 168)  src = nullptr;
    else if (row < 680)  src = qw1 + (size_t)(row - 168) * D_;
    else if (row < 744)  src = kw1 + (size_t)(row - 680) * D_;
    else if (row < 752)  src = ww1 + (size_t)(row - 744) * D_;
    else if (row < 2800) src = qw2 + (size_t)(row - 752) * D_;
    else if (row < 2928) src = kw2 + (size_t)(row - 2800) * D_;
    else if (row < 2944) src = ww2 + (size_t)(row - 2928) * D_;
    else if (row < 3008) src = w1s + (size_t)(row - 2944) * D_;
    float4 v = src ? *(const float4*)(src + col) : make_float4(0.f, 0.f, 0.f, 0.f);
    float vv[4] = {v.x, v.y, v.z, v.w};
    unsigned long long hp = 0, lp = 0;
#pragma unroll
    for (int e = 0; e < 4; ++e) {
        u16 hb = f2bf(vv[e]);
        u16 lb = f2bf(vv[e] - bf2f(hb));
        hp |= ((unsigned long long)hb) << (16 * e);
        lp |= ((unsigned long long)lb) << (16 * e);
    }
    *(unsigned long long*)&Wh[(size_t)row * D_ + col] = hp;
    *(unsigned long long*)&Wl[(size_t)row * D_ + col] = lp;
}

// ---------------- projection GEMM: P[4096,3072] = x @ Wsplit^T (split bf16 MFMA) --------
__global__ __launch_bounds__(256, 2) void proj_gemm(
    const float* __restrict__ X, const u16* __restrict__ Wh, const u16* __restrict__ Wl,
    u16* __restrict__ Ph, u16* __restrict__ Pl) {
    __shared__ u16 Ah[128 * 32], Al[128 * 32], Bh[128 * 32], Bl[128 * 32];
    int tid = threadIdx.x;
    int wave = tid >> 6, lane = tid & 63;
    int bm = blockIdx.x * 128, bn = blockIdx.y * 128;
    int wt = wave >> 1, wn = wave & 1;
    f32x16 acc[2][2];
#pragma unroll
    for (int i = 0; i < 2; ++i)
#pragma unroll
        for (int j = 0; j < 2; ++j)
#pragma unroll
            for (int r = 0; r < 16; ++r) acc[i][j][r] = 0.f;

    int brow = lane >> 2;            // 0..15
    int bcol = (lane & 3) * 8;

    for (int kb = 0; kb < D_; kb += 32) {
        // B (weights) via async global->LDS, already bf16 hi/lo
#pragma unroll
        for (int rep = 0; rep < 2; ++rep) {
            int rb = (wave * 2 + rep) * 16;
            size_t wrow = (size_t)(bn + rb + brow);
            gload16(Wh + wrow * D_ + kb + bcol, &Bh[rb * 32]);
            gload16(Wl + wrow * D_ + kb + bcol, &Bl[rb * 32]);
        }
        // A (x) staged manually with fp32 -> hi/lo split
#pragma unroll
        for (int it = 0; it < 2; ++it) {
            int slot = it * 256 + tid;
            int r = slot >> 2, q = slot & 3;
            const float* xp = X + (size_t)(bm + r) * D_ + kb + q * 8;
            float4 v0 = *(const float4*)xp;
            float4 v1 = *(const float4*)(xp + 4);
            float vv[8] = {v0.x, v0.y, v0.z, v0.w, v1.x, v1.y, v1.z, v1.w};
            bf16x8 hv, lv;
#pragma unroll
            for (int e = 0; e < 8; ++e) {
                u16 hb = f2bf(vv[e]);
                hv[e] = (short)hb;
                lv[e] = (short)f2bf(vv[e] - bf2f(hb));
            }
            *(bf16x8*)&Ah[r * 32 + q * 8] = hv;
            *(bf16x8*)&Al[r * 32 + q * 8] = lv;
        }
        __syncthreads();
#pragma unroll
        for (int ks = 0; ks < 2; ++ks) {
            int fm = lane & 31;
            int fk = ks * 16 + (lane >> 5) * 8;
            bf16x8 ah[2], al[2], bh[2], bl[2];
#pragma unroll
            for (int ti = 0; ti < 2; ++ti) {
                int m0 = wt * 64 + ti * 32;
                int n0 = wn * 64 + ti * 32;
                ah[ti] = *(const bf16x8*)&Ah[(m0 + fm) * 32 + fk];
                al[ti] = *(const bf16x8*)&Al[(m0 + fm) * 32 + fk];
                bh[ti] = *(const bf16x8*)&Bh[(n0 + fm) * 32 + fk];
                bl[ti] = *(const bf16x8*)&Bl[(n0 + fm) * 32 + fk];
            }
#pragma unroll
            for (int ti = 0; ti < 2; ++ti)
#pragma unroll
                for (int tj = 0; tj < 2; ++tj) {
                    acc[ti][tj] = __builtin_amdgcn_mfma_f32_32x32x16_bf16(ah[ti], bh[tj], acc[ti][tj], 0, 0, 0);
                    acc[ti][tj] = __builtin_amdgcn_mfma_f32_32x32x16_bf16(ah[ti], bl[tj], acc[ti][tj], 0, 0, 0);
                    acc[ti][tj] = __builtin_amdgcn_mfma_f32_32x32x16_bf16(al[ti], bh[tj], acc[ti][tj], 0, 0, 0);
                }
        }
        __syncthreads();
    }
    // epilogue: store hi/lo bf16 (C layout: col=lane&31, row=(r&3)+8*(r>>2)+4*(lane>>5))
#pragma unroll
    for (int ti = 0; ti < 2; ++ti)
#pragma unroll
        for (int tj = 0; tj < 2; ++tj)
#pragma unroll
            for (int r = 0; r < 16; ++r) {
                int row = bm + wt * 64 + ti * 32 + (r & 3) + 8 * (r >> 2) + 4 * (lane >> 5);
                int col = bn + wn * 64 + tj * 32 + (lane & 31);
                float v = acc[ti][tj][r];
                u16 hb = f2bf(v);
                Ph[(size_t)row * LDN + col] = hb;
                Pl[(size_t)row * LDN + col] = f2bf(v - bf2f(hb));
            }
}

// ---------------- selector layers 2-3 + softmax (layer1 comes from proj GEMM) ----------
__global__ void selector2(const u16* __restrict__ Ph, const u16* __restrict__ Pl,
                          const float* __restrict__ msd, const float* __restrict__ s1,
                          const float* __restrict__ b1, const float* __restrict__ w2,
                          const float* __restrict__ b2, const float* __restrict__ w3,
                          const float* __restrict__ b3, float* __restrict__ PR) {
    __shared__ float h1s[4][64];
    __shared__ float h2s[4][64];
    __shared__ float lg[4][3];
    int tid = threadIdx.x;
    int slot = tid >> 6, j = tid & 63;
    int bt = blockIdx.x * 4 + slot;
    int b = bt >> 11, t = bt & 2047;
    size_t pidx = (size_t)bt * LDN + SELO + j;
    float v = bf2f(Ph[pidx]) + bf2f(Pl[pidx])
            + msd[b * 64 + j] + 0.1f * ((float)t / (float)T_) * s1[j] + b1[j];
    h1s[slot][j] = fmaxf(v, 0.f);
    __syncthreads();
    float a2 = b2[j];
#pragma unroll 8
    for (int d = 0; d < 64; ++d) a2 = fmaf(h1s[slot][d], w2[j * 64 + d], a2);
    h2s[slot][j] = fmaxf(a2, 0.f);
    __syncthreads();
    if (j < 3) {
        float a3 = b3[j];
        for (int d = 0; d < 64; ++d) a3 = fmaf(h2s[slot][d], w3[j * 64 + d], a3);
        lg[slot][j] = a3;
    }
    __syncthreads();
    if (j == 0) {
        float m = fmaxf(lg[slot][0], fmaxf(lg[slot][1], lg[slot][2]));
        float e0 = expf(lg[slot][0] - m), e1 = expf(lg[slot][1] - m), e2 = expf(lg[slot][2] - m);
        float inv = 1.f / (e0 + e1 + e2);
        PR[bt * 3 + 0] = e0 * inv;
        PR[bt * 3 + 1] = e1 * inv;
        PR[bt * 3 + 2] = e2 * inv;
    }
}

// ---------------- fused relu-attention score kernel (split bf16 MFMA) ----------------
__global__ __launch_bounds__(256, 2) void score_kernel(
    const u16* __restrict__ Ph, const u16* __restrict__ Pl,
    const float* __restrict__ PR, float* __restrict__ out) {
    __shared__ u16 Qh[128 * 32], Ql[128 * 32], Kh[128 * 32], Kl[128 * 32];
    __shared__ float wp[128 * 28];
    int tid = threadIdx.x;
    int wave = tid >> 6, lane = tid & 63;
    int b  = blockIdx.z;
    int t0 = blockIdx.y * 128;
    int s0 = blockIdx.x * 128;
    int wt = wave >> 1, wn = wave & 1;

    // build wp[row][g] = w_g(row) * prob_cfg(row)
    for (int idx = tid; idx < 128 * 28; idx += 256) {
        int r = idx / 28, g = idx - r * 28;
        int wcol = (g < 4) ? (WO0 + g) : ((g < 12) ? (WO1 + g - 4) : (WO2 + g - 12));
        int cfg  = (g < 4) ? 0 : ((g < 12) ? 1 : 2);
        size_t prow = (size_t)(b * T_ + t0 + r);
        float w = bf2f(Ph[prow * LDN + wcol]) + bf2f(Pl[prow * LDN + wcol]);
        wp[r * 28 + g] = w * PR[prow * 3 + cfg];
    }

    f32x16 outacc[2][2], dots[2][2];
#pragma unroll
    for (int i = 0; i < 2; ++i)
#pragma unroll
        for (int j = 0; j < 2; ++j)
#pragma unroll
            for (int r = 0; r < 16; ++r) { outacc[i][j][r] = 0.f; dots[i][j][r] = 0.f; }

    int srow = lane >> 2, scol8 = (lane & 3) * 8;
    __syncthreads();

    // 84 chunks of 32 d-columns: (cfg, head, kb)
    for (int c = 0; c < 84; ++c) {
        int qcol, kcol, g; bool last;
        if (c < 4)       { g = c; qcol = QO0 + c * 32; kcol = KO0; last = true; }
        else if (c < 20) { int u = c - 4;  int h = u >> 1, kb = u & 1; g = 4 + h;
                           qcol = QO1 + h * 64 + kb * 32;  kcol = KO1 + kb * 32; last = (kb == 1); }
        else             { int u = c - 20; int h = u >> 2, kb = u & 3; g = 12 + h;
                           qcol = QO2 + h * 128 + kb * 32; kcol = KO2 + kb * 32; last = (kb == 3); }
#pragma unroll
        for (int rep = 0; rep < 2; ++rep) {
            int rb = (wave * 2 + rep) * 16;
            size_t qrow = (size_t)(b * T_ + t0 + rb + srow);
            size_t krow = (size_t)(b * T_ + s0 + rb + srow);
            gload16(Ph + qrow * LDN + qcol + scol8, &Qh[rb * 32]);
            gload16(Pl + qrow * LDN + qcol + scol8, &Ql[rb * 32]);
            gload16(Ph + krow * LDN + kcol + scol8, &Kh[rb * 32]);
            gload16(Pl + krow * LDN + kcol + scol8, &Kl[rb * 32]);
        }
        __syncthreads();
#pragma unroll
        for (int ks = 0; ks < 2; ++ks) {
            int fm = lane & 31;
            int fk = ks * 16 + (lane >> 5) * 8;
            bf16x8 qh[2], ql[2], kh[2], kl[2];
#pragma unroll
            for (int ti = 0; ti < 2; ++ti) {
                int m0 = wt * 64 + ti * 32;
                int n0 = wn * 64 + ti * 32;
                qh[ti] = *(const bf16x8*)&Qh[(m0 + fm) * 32 + fk];
                ql[ti] = *(const bf16x8*)&Ql[(m0 + fm) * 32 + fk];
                kh[ti] = *(const bf16x8*)&Kh[(n0 + fm) * 32 + fk];
                kl[ti] = *(const bf16x8*)&Kl[(n0 + fm) * 32 + fk];
            }
#pragma unroll
            for (int ti = 0; ti < 2; ++ti)
#pragma unroll
                for (int tj = 0; tj < 2; ++tj) {
                    dots[ti][tj] = __builtin_amdgcn_mfma_f32_32x32x16_bf16(qh[ti], kh[tj], dots[ti][tj], 0, 0, 0);
                    dots[ti][tj] = __builtin_amdgcn_mfma_f32_32x32x16_bf16(qh[ti], kl[tj], dots[ti][tj], 0, 0, 0);
                    dots[ti][tj] = __builtin_amdgcn_mfma_f32_32x32x16_bf16(ql[ti], kh[tj], dots[ti][tj], 0, 0, 0);
                }
        }
        if (last) {
#pragma unroll
            for (int ti = 0; ti < 2; ++ti)
#pragma unroll
                for (int tj = 0; tj < 2; ++tj)
#pragma unroll
                    for (int r = 0; r < 16; ++r) {
                        int trow = wt * 64 + ti * 32 + (r & 3) + 8 * (r >> 2) + 4 * (lane >> 5);
                        outacc[ti][tj][r] += fmaxf(dots[ti][tj][r], 0.f) * wp[trow * 28 + g];
                        dots[ti][tj][r] = 0.f;
                    }
        }
        __syncthreads();
    }
#pragma unroll
    for (int ti = 0; ti < 2; ++ti)
#pragma unroll
        for (int tj = 0; tj < 2; ++tj)
#pragma unroll
            for (int r = 0; r < 16; ++r) {
                int trow = wt * 64 + ti * 32 + (r & 3) + 8 * (r >> 2) + 4 * (lane >> 5);
                int scol = wn * 64 + tj * 32 + (lane & 31);
                out[(size_t)(b * T_ + t0 + trow) * T_ + (s0 + scol)] = outacc[ti][tj][r];
            }
}

extern "C" void kernel_launch(void* const* d_in, const int* in_sizes, int n_in,
                              void* d_out, int out_size, void* d_ws, size_t ws_size,
                              hipStream_t stream) {
    const float* x   = (const float*)d_in[0];
    const float* w1  = (const float*)d_in[1];
    const float* b1  = (const float*)d_in[2];
    const float* w2  = (const float*)d_in[3];
    const float* b2  = (const float*)d_in[4];
    const float* w3  = (const float*)d_in[5];
    const float* b3  = (const float*)d_in[6];
    const float* qw0 = (const float*)d_in[7];
    const float* kw0 = (const float*)d_in[8];
    const float* ww0 = (const float*)d_in[9];
    const float* qw1 = (const float*)d_in[10];
    const float* kw1 = (const float*)d_in[11];
    const float* ww1 = (const float*)d_in[12];
    const float* qw2 = (const float*)d_in[13];
    const float* kw2 = (const float*)d_in[14];
    const float* ww2 = (const float*)d_in[15];
    float* out = (float*)d_out;

    // workspace carve-up (floats first, then bf16 buffers) — ~63.3 MB total
    float* fb = (float*)d_ws;
    float* MS  = fb; fb += 2048;
    float* MSD = fb; fb += 128;
    float* S1  = fb; fb += 64;
    float* PR  = fb; fb += (size_t)M_ * 3;
    float* PA  = fb; fb += (size_t)B_ * 16 * D_;
    float* PA2 = fb; fb += (size_t)B_ * 16 * D_;
    u16* ub = (u16*)fb;
    u16* Wh = ub; ub += (size_t)LDN * D_;
    u16* Wl = ub; ub += (size_t)LDN * D_;
    u16* Ph = ub; ub += (size_t)M_ * LDN;
    u16* Pl = ub; ub += (size_t)M_ * LDN;

    stats_partial<<<dim3(D_ / 256, 16, B_), 256, 0, stream>>>(x, PA, PA2);
    stats_final<<<dim3((B_ * D_ + 255) / 256), 256, 0, stream>>>(PA, PA2, MS);
    msdot<<<dim3(B_), 64, 0, stream>>>(MS, w1, MSD, S1);
    split_w<<<dim3(LDN), 256, 0, stream>>>(qw0, kw0, ww0, qw1, kw1, ww1,
                                           qw2, kw2, ww2, w1, Wh, Wl);
    proj_gemm<<<dim3(M_ / 128, LDN / 128), 256, 0, stream>>>(x, Wh, Wl, Ph, Pl);
    selector2<<<dim3(M_ / 4), 256, 0, stream>>>(Ph, Pl, MSD, S1, b1, w2, b2, w3, b3, PR);
    score_kernel<<<dim3(T_ / 128, T_ / 128, B_), 256, 0, stream>>>(Ph, Pl, PR, out);
}

// Round 3
// 296.717 us; speedup vs baseline: 5.3688x; 1.4513x over previous
//
#include <hip/hip_runtime.h>
#include <cstdint>
#include <cstddef>
#include <math.h>

#define B_ 2
#define T_ 2048
#define D_ 1024
#define M_ (B_*T_)

// column layout of P (= row layout of W concat), all offsets multiples of 8
#define QO0 0
#define KO0 128
#define WO0 160
// pad 164..167 (zero)
#define QO1 168
#define KO1 680
#define WO1 744
#define QO2 752
#define KO2 2800
#define WO2 2928
#define SELO 2944
// zero pad 3008..3071
#define LDN 3072

typedef float f32x16 __attribute__((ext_vector_type(16)));
typedef short bf16x8 __attribute__((ext_vector_type(8)));
typedef unsigned short u16;

__device__ __forceinline__ u16 f2bf(float f) {
    unsigned int u = __float_as_uint(f);
    unsigned int r = (u + 0x7fffu + ((u >> 16) & 1u)) >> 16;   // RNE
    return (u16)r;
}
__device__ __forceinline__ float bf2f(u16 b) {
    return __uint_as_float(((unsigned int)b) << 16);
}

// async global->LDS, 16B per lane, dest = wave-uniform base + lane*16
__device__ __forceinline__ void gload16(const void* g, void* l) {
    __builtin_amdgcn_global_load_lds(
        (const __attribute__((address_space(1))) unsigned int*)g,
        (__attribute__((address_space(3))) unsigned int*)l,
        16, 0, 0);
}

// stage one 16-row x 32-col u16 plane-slice: rows rg*16..rg*16+15 from src rows
// (row-major, row_stride u16 elements), cols k0..k0+31 -> dst + rg*512 (row-major [16][32])
__device__ __forceinline__ void stage_plane(const u16* src_base, int row_stride, int k0,
                                            int rg, int lane, u16* dst) {
    int row = rg * 16 + (lane >> 2);
    const u16* s = src_base + (size_t)row * row_stride + k0 + (lane & 3) * 8;
    gload16(s, dst + rg * 512);
}

// ---------------- stats: mean + std(ddof=1) over t, per (b,d) ----------------
__global__ void stats_partial(const float* __restrict__ x,
                              float* __restrict__ part, float* __restrict__ part2) {
    int d  = blockIdx.x * 256 + threadIdx.x;
    int tc = blockIdx.y;
    int b  = blockIdx.z;
    const float* p = x + (size_t)b * T_ * D_ + (size_t)tc * 128 * D_ + d;
    float s = 0.f, s2 = 0.f;
    for (int t = 0; t < 128; ++t) {
        float v = p[(size_t)t * D_];
        s += v; s2 += v * v;
    }
    part [(b * 16 + tc) * D_ + d] = s;
    part2[(b * 16 + tc) * D_ + d] = s2;
}

__global__ void stats_final(const float* __restrict__ part, const float* __restrict__ part2,
                            float* __restrict__ ms) {
    int idx = blockIdx.x * 256 + threadIdx.x;
    if (idx >= B_ * D_) return;
    int b = idx / D_, d = idx % D_;
    float s = 0.f, s2 = 0.f;
    for (int i = 0; i < 16; ++i) {
        s  += part [(b * 16 + i) * D_ + d];
        s2 += part2[(b * 16 + i) * D_ + d];
    }
    float mean = s / (float)T_;
    float var  = (s2 - (float)T_ * mean * mean) / (float)(T_ - 1);
    ms[idx] = mean + sqrtf(fmaxf(var, 0.f));
}

// msd[b][j] = ms[b,:] . w1[j,:] ;  s1[j] = sum_d w1[j][d]
__global__ void msdot(const float* __restrict__ ms, const float* __restrict__ w1,
                      float* __restrict__ msd, float* __restrict__ s1) {
    int b = blockIdx.x, j = threadIdx.x;
    const float* wr = w1 + (size_t)j * D_;
    const float* mr = ms + (size_t)b * D_;
    float am = 0.f, as = 0.f;
    for (int d4 = 0; d4 < D_ / 4; ++d4) {
        float4 w = *(const float4*)(wr + d4 * 4);
        float4 m = *(const float4*)(mr + d4 * 4);
        am += w.x * m.x + w.y * m.y + w.z * m.z + w.w * m.w;
        as += w.x + w.y + w.z + w.w;
    }
    msd[b * 64 + j] = am;
    if (b == 0) s1[j] = as;
}

// ---------------- weight concat -> bf16: Wh[3072][1024] ----------------
__global__ void split_w(const float* __restrict__ qw0, const float* __restrict__ kw0,
                        const float* __restrict__ ww0, const float* __restrict__ qw1,
                        const float* __restrict__ kw1, const float* __restrict__ ww1,
                        const float* __restrict__ qw2, const float* __restrict__ kw2,
                        const float* __restrict__ ww2, const float* __restrict__ w1s,
                        u16* __restrict__ Wh) {
    int row = blockIdx.x;
    int col = threadIdx.x * 4;
    const float* src = nullptr;
    if      (row < 128)  src = qw0 + (size_t)row * D_;
    else if (row < 160)  src = kw0 + (size_t)(row - 128) * D_;
    else if (row < 164)  src = ww0 + (size_t)(row - 160) * D_;
    else if (row < 168)  src = nullptr;
    else if (row < 680)  src = qw1 + (size_t)(row - 168) * D_;
    else if (row < 744)  src = kw1 + (size_t)(row - 680) * D_;
    else if (row < 752)  src = ww1 + (size_t)(row - 744) * D_;
    else if (row < 2800) src = qw2 + (size_t)(row - 752) * D_;
    else if (row < 2928) src = kw2 + (size_t)(row - 2800) * D_;
    else if (row < 2944) src = ww2 + (size_t)(row - 2928) * D_;
    else if (row < 3008) src = w1s + (size_t)(row - 2944) * D_;
    float4 v = src ? *(const float4*)(src + col) : make_float4(0.f, 0.f, 0.f, 0.f);
    ushort4 h;
    h.x = f2bf(v.x); h.y = f2bf(v.y); h.z = f2bf(v.z); h.w = f2bf(v.w);
    *(ushort4*)&Wh[(size_t)row * D_ + col] = h;
}

// ---------------- x -> bf16 hi/lo split ----------------
__global__ void split_x(const float* __restrict__ x, u16* __restrict__ Xh, u16* __restrict__ Xl) {
    size_t i = ((size_t)blockIdx.x * 256 + threadIdx.x) * 4;
    float4 v = *(const float4*)(x + i);
    float vv[4] = {v.x, v.y, v.z, v.w};
    ushort4 h, l;
    u16 hb;
    hb = f2bf(vv[0]); h.x = hb; l.x = f2bf(vv[0] - bf2f(hb));
    hb = f2bf(vv[1]); h.y = hb; l.y = f2bf(vv[1] - bf2f(hb));
    hb = f2bf(vv[2]); h.z = hb; l.z = f2bf(vv[2] - bf2f(hb));
    hb = f2bf(vv[3]); h.w = hb; l.w = f2bf(vv[3] - bf2f(hb));
    *(ushort4*)&Xh[i] = h;
    *(ushort4*)&Xl[i] = l;
}

// ---------------- projection GEMM: Ph[4096,3072] = bf16( (Xh+Xl) @ Wh^T ) ----------------
__global__ __launch_bounds__(256, 3) void proj_gemm(
    const u16* __restrict__ Xh, const u16* __restrict__ Xl, const u16* __restrict__ Wh,
    u16* __restrict__ Ph) {
    __shared__ u16 Ah[2][4096], Al[2][4096], Bh[2][4096];
    int tid = threadIdx.x;
    int wave = tid >> 6, lane = tid & 63;
    int bm = blockIdx.x * 128, bn = blockIdx.y * 128;
    int wt = wave >> 1, wn = wave & 1;
    int fm = lane & 31, half8 = (lane >> 5) * 8;
    f32x16 acc[2][2];
#pragma unroll
    for (int i = 0; i < 2; ++i)
#pragma unroll
        for (int j = 0; j < 2; ++j)
#pragma unroll
            for (int r = 0; r < 16; ++r) acc[i][j][r] = 0.f;

    const u16* xh = Xh + (size_t)bm * D_;
    const u16* xl = Xl + (size_t)bm * D_;
    const u16* wh = Wh + (size_t)bn * D_;

    auto stage = [&](int buf, int k0) {
        for (int j = wave; j < 24; j += 4) {
            int pl = j >> 3, rg = j & 7;
            if      (pl == 0) stage_plane(xh, D_, k0, rg, lane, Ah[buf]);
            else if (pl == 1) stage_plane(xl, D_, k0, rg, lane, Al[buf]);
            else              stage_plane(wh, D_, k0, rg, lane, Bh[buf]);
        }
    };

    stage(0, 0);
    for (int kc = 0; kc < 32; ++kc) {
        __syncthreads();
        if (kc + 1 < 32) stage((kc + 1) & 1, (kc + 1) * 32);
        const u16* ah = Ah[kc & 1];
        const u16* al = Al[kc & 1];
        const u16* bh = Bh[kc & 1];
#pragma unroll
        for (int ks = 0; ks < 2; ++ks) {
            int fk = ks * 16 + half8;
            bf16x8 a_h[2], a_l[2], b_h[2];
#pragma unroll
            for (int t = 0; t < 2; ++t) {
                a_h[t] = *(const bf16x8*)&ah[(wt * 64 + t * 32 + fm) * 32 + fk];
                a_l[t] = *(const bf16x8*)&al[(wt * 64 + t * 32 + fm) * 32 + fk];
                b_h[t] = *(const bf16x8*)&bh[(wn * 64 + t * 32 + fm) * 32 + fk];
            }
#pragma unroll
            for (int ti = 0; ti < 2; ++ti)
#pragma unroll
                for (int tj = 0; tj < 2; ++tj) {
                    acc[ti][tj] = __builtin_amdgcn_mfma_f32_32x32x16_bf16(a_h[ti], b_h[tj], acc[ti][tj], 0, 0, 0);
                    acc[ti][tj] = __builtin_amdgcn_mfma_f32_32x32x16_bf16(a_l[ti], b_h[tj], acc[ti][tj], 0, 0, 0);
                }
        }
    }
#pragma unroll
    for (int ti = 0; ti < 2; ++ti)
#pragma unroll
        for (int tj = 0; tj < 2; ++tj)
#pragma unroll
            for (int r = 0; r < 16; ++r) {
                int row = bm + wt * 64 + ti * 32 + (r & 3) + 8 * (r >> 2) + 4 * (lane >> 5);
                int col = bn + wn * 64 + tj * 32 + (lane & 31);
                Ph[(size_t)row * LDN + col] = f2bf(acc[ti][tj][r]);
            }
}

// ---------------- selector layers 2-3 + softmax (layer1 from proj GEMM) ----------
__global__ void selector2(const u16* __restrict__ Ph,
                          const float* __restrict__ msd, const float* __restrict__ s1,
                          const float* __restrict__ b1, const float* __restrict__ w2,
                          const float* __restrict__ b2, const float* __restrict__ w3,
                          const float* __restrict__ b3, float* __restrict__ PR) {
    __shared__ float h1s[4][64];
    __shared__ float h2s[4][64];
    __shared__ float lg[4][3];
    int tid = threadIdx.x;
    int slot = tid >> 6, j = tid & 63;
    int bt = blockIdx.x * 4 + slot;
    int b = bt >> 11, t = bt & 2047;
    size_t pidx = (size_t)bt * LDN + SELO + j;
    float v = bf2f(Ph[pidx])
            + msd[b * 64 + j] + 0.1f * ((float)t / (float)T_) * s1[j] + b1[j];
    h1s[slot][j] = fmaxf(v, 0.f);
    __syncthreads();
    float a2 = b2[j];
#pragma unroll 8
    for (int d = 0; d < 64; ++d) a2 = fmaf(h1s[slot][d], w2[j * 64 + d], a2);
    h2s[slot][j] = fmaxf(a2, 0.f);
    __syncthreads();
    if (j < 3) {
        float a3 = b3[j];
        for (int d = 0; d < 64; ++d) a3 = fmaf(h2s[slot][d], w3[j * 64 + d], a3);
        lg[slot][j] = a3;
    }
    __syncthreads();
    if (j == 0) {
        float m = fmaxf(lg[slot][0], fmaxf(lg[slot][1], lg[slot][2]));
        float e0 = expf(lg[slot][0] - m), e1 = expf(lg[slot][1] - m), e2 = expf(lg[slot][2] - m);
        float inv = 1.f / (e0 + e1 + e2);
        PR[bt * 3 + 0] = e0 * inv;
        PR[bt * 3 + 1] = e1 * inv;
        PR[bt * 3 + 2] = e2 * inv;
    }
}

__device__ __forceinline__ int qcol_of(int c) {
    if (c < 2)  return QO0 + c * 64;
    if (c < 10) return QO1 + (c - 2) * 64;
    int u = c - 10;
    return QO2 + (u >> 1) * 128 + (u & 1) * 64;
}

// ---------------- fused relu-attention score kernel (bf16 MFMA, K-resident) ----------------
__global__ __launch_bounds__(256, 2) void score_kernel(
    const u16* __restrict__ Ph, const float* __restrict__ PR, float* __restrict__ out) {
    __shared__ u16 Qs[2][8192];    // 2 bufs x 2 planes x [128][32]
    __shared__ u16 Ks[4 * 4096];   // up to 4 planes x [128][32]
    __shared__ float wpT[28 * 128];
    int tid = threadIdx.x;
    int wave = tid >> 6, lane = tid & 63;
    int wt = wave >> 1, wn = wave & 1;
    int fm = lane & 31, half8 = (lane >> 5) * 8;

    // XCD-aware swizzle: keep blocks sharing a Q-tile (same b,t0) on one XCD
    int n = blockIdx.z * 256 + blockIdx.y * 16 + blockIdx.x;
    int p = (n & 7) * 4 + (n >> 7);
    int xb = (n >> 3) & 15;
    int b = p >> 4, yb = p & 15;
    int t0 = yb * 128, s0 = xb * 128;

    const u16* Pq = Ph + (size_t)(b * T_ + t0) * LDN;  // Q rows
    const u16* Pk = Ph + (size_t)(b * T_ + s0) * LDN;  // K rows

    auto stageQ = [&](int buf, int qcol) {
#pragma unroll
        for (int i = 0; i < 4; ++i) {
            int j = (wave << 2) + i;
            int pl = j >> 3, rg = j & 7;
            stage_plane(Pq, LDN, qcol + pl * 32, rg, lane, &Qs[buf][pl * 4096]);
        }
    };
    auto stageK = [&](int kbase, int nplanes) {
        for (int j = wave; j < nplanes * 8; j += 4) {
            int pl = j >> 3, rg = j & 7;
            stage_plane(Pk, LDN, kbase + pl * 32, rg, lane, &Ks[pl * 4096]);
        }
    };

    // prologue staging: K for cfg0 + Q chunk 0
    stageK(KO0, 1);
    stageQ(0, qcol_of(0));

    // wp transposed: wpT[g][row] = w_g(row) * prob_cfg(row)
    for (int idx = tid; idx < 28 * 128; idx += 256) {
        int g = idx >> 7, r = idx & 127;
        int wcol = (g < 4) ? (WO0 + g) : ((g < 12) ? (WO1 + g - 4) : (WO2 + g - 12));
        int cfg  = (g < 4) ? 0 : ((g < 12) ? 1 : 2);
        size_t prow = (size_t)(b * T_ + t0 + r);
        wpT[g * 128 + r] = bf2f(Ph[prow * LDN + wcol]) * PR[prow * 3 + cfg];
    }

    f32x16 outacc[2][2], dots[2][2];
#pragma unroll
    for (int i = 0; i < 2; ++i)
#pragma unroll
        for (int j = 0; j < 2; ++j)
#pragma unroll
            for (int r = 0; r < 16; ++r) { outacc[i][j][r] = 0.f; dots[i][j][r] = 0.f; }

    for (int c = 0; c < 42; ++c) {
        int kp0, kp1, gMid, gEnd;
        if (c < 2)       { kp0 = 0; kp1 = 0; gMid = 2 * c; gEnd = 2 * c + 1; }
        else if (c < 10) { kp0 = 0; kp1 = 1; gMid = -1; gEnd = 4 + (c - 2); }
        else { int u = c - 10; int h = u >> 1, kb = u & 1;
               kp0 = kb * 2; kp1 = kb * 2 + 1; gMid = -1; gEnd = kb ? (12 + h) : -1; }

        __syncthreads();   // staged data (Q[c], K for this cfg, wpT on c==0) ready
        if (c < 41) stageQ((c + 1) & 1, qcol_of(c + 1));   // overlap with compute below

        const u16* qb = Qs[c & 1];
#pragma unroll
        for (int ks = 0; ks < 4; ++ks) {
            int fcol = (ks & 1) * 16 + half8;
            int kp = (ks < 2) ? kp0 : kp1;
            bf16x8 kf[2], qf[2];
#pragma unroll
            for (int tj = 0; tj < 2; ++tj)
                kf[tj] = *(const bf16x8*)&Ks[kp * 4096 + (wn * 64 + tj * 32 + fm) * 32 + fcol];
#pragma unroll
            for (int ti = 0; ti < 2; ++ti)
                qf[ti] = *(const bf16x8*)&qb[(ks >> 1) * 4096 + (wt * 64 + ti * 32 + fm) * 32 + fcol];
#pragma unroll
            for (int ti = 0; ti < 2; ++ti)
#pragma unroll
                for (int tj = 0; tj < 2; ++tj)
                    dots[ti][tj] = __builtin_amdgcn_mfma_f32_32x32x16_bf16(qf[ti], kf[tj], dots[ti][tj], 0, 0, 0);

            int g = (ks == 1) ? gMid : ((ks == 3) ? gEnd : -1);
            if (g >= 0) {
#pragma unroll
                for (int ti = 0; ti < 2; ++ti) {
                    int rowbase = wt * 64 + ti * 32 + 4 * (lane >> 5);
#pragma unroll
                    for (int rq = 0; rq < 4; ++rq) {
                        float4 w4 = *(const float4*)&wpT[g * 128 + rowbase + rq * 8];
                        float wv[4] = {w4.x, w4.y, w4.z, w4.w};
#pragma unroll
                        for (int tj = 0; tj < 2; ++tj)
#pragma unroll
                            for (int r2 = 0; r2 < 4; ++r2) {
                                int r = rq * 4 + r2;
                                outacc[ti][tj][r] += fmaxf(dots[ti][tj][r], 0.f) * wv[r2];
                                dots[ti][tj][r] = 0.f;
                            }
                    }
                }
            }
        }
        // cfg boundaries: all waves must finish reading Ks before restage
        if (c == 1)      { __syncthreads(); stageK(KO1, 2); }
        else if (c == 9) { __syncthreads(); stageK(KO2, 4); }
    }

#pragma unroll
    for (int ti = 0; ti < 2; ++ti)
#pragma unroll
        for (int tj = 0; tj < 2; ++tj)
#pragma unroll
            for (int r = 0; r < 16; ++r) {
                int trow = wt * 64 + ti * 32 + (r & 3) + 8 * (r >> 2) + 4 * (lane >> 5);
                int scol = wn * 64 + tj * 32 + (lane & 31);
                out[(size_t)(b * T_ + t0 + trow) * T_ + (s0 + scol)] = outacc[ti][tj][r];
            }
}

extern "C" void kernel_launch(void* const* d_in, const int* in_sizes, int n_in,
                              void* d_out, int out_size, void* d_ws, size_t ws_size,
                              hipStream_t stream) {
    const float* x   = (const float*)d_in[0];
    const float* w1  = (const float*)d_in[1];
    const float* b1  = (const float*)d_in[2];
    const float* w2  = (const float*)d_in[3];
    const float* b2  = (const float*)d_in[4];
    const float* w3  = (const float*)d_in[5];
    const float* b3  = (const float*)d_in[6];
    const float* qw0 = (const float*)d_in[7];
    const float* kw0 = (const float*)d_in[8];
    const float* ww0 = (const float*)d_in[9];
    const float* qw1 = (const float*)d_in[10];
    const float* kw1 = (const float*)d_in[11];
    const float* ww1 = (const float*)d_in[12];
    const float* qw2 = (const float*)d_in[13];
    const float* kw2 = (const float*)d_in[14];
    const float* ww2 = (const float*)d_in[15];
    float* out = (float*)d_out;

    // workspace carve-up: ~48 MB total
    float* fb = (float*)d_ws;
    float* MS  = fb; fb += 2048;
    float* MSD = fb; fb += 128;
    float* S1  = fb; fb += 64;
    float* PR  = fb; fb += (size_t)M_ * 3;
    float* PA  = fb; fb += (size_t)B_ * 16 * D_;
    float* PA2 = fb; fb += (size_t)B_ * 16 * D_;
    u16* ub = (u16*)fb;
    u16* Wh = ub; ub += (size_t)LDN * D_;      // 6.3 MB
    u16* Xh = ub; ub += (size_t)M_ * D_;       // 8 MB
    u16* Xl = ub; ub += (size_t)M_ * D_;       // 8 MB
    u16* Ph = ub; ub += (size_t)M_ * LDN;      // 25 MB

    stats_partial<<<dim3(D_ / 256, 16, B_), 256, 0, stream>>>(x, PA, PA2);
    stats_final<<<dim3((B_ * D_ + 255) / 256), 256, 0, stream>>>(PA, PA2, MS);
    msdot<<<dim3(B_), 64, 0, stream>>>(MS, w1, MSD, S1);
    split_w<<<dim3(LDN), 256, 0, stream>>>(qw0, kw0, ww0, qw1, kw1, ww1,
                                           qw2, kw2, ww2, w1, Wh);
    split_x<<<dim3((M_ * D_) / 1024), 256, 0, stream>>>(x, Xh, Xl);
    proj_gemm<<<dim3(M_ / 128, LDN / 128), 256, 0, stream>>>(Xh, Xl, Wh, Ph);
    selector2<<<dim3(M_ / 4), 256, 0, stream>>>(Ph, MSD, S1, b1, w2, b2, w3, b3, PR);
    score_kernel<<<dim3(T_ / 128, T_ / 128, B_), 256, 0, stream>>>(Ph, PR, out);
}

// Round 4
// 273.486 us; speedup vs baseline: 5.8249x; 1.0849x over previous
//
#include <hip/hip_runtime.h>
#include <cstdint>
#include <cstddef>
#include <math.h>

#define B_ 2
#define T_ 2048
#define D_ 1024
#define M_ (B_*T_)

// column layout of P (= row layout of W concat), all offsets multiples of 8
#define QO0 0
#define KO0 128
#define WO0 160
// pad 164..167 (zero)
#define QO1 168
#define KO1 680
#define WO1 744
#define QO2 752
#define KO2 2800
#define WO2 2928
#define SELO 2944
// zero pad 3008..3071
#define LDN 3072

typedef float f32x16 __attribute__((ext_vector_type(16)));
typedef short bf16x8 __attribute__((ext_vector_type(8)));
typedef unsigned short u16;

__device__ __forceinline__ u16 f2bf(float f) {
    unsigned int u = __float_as_uint(f);
    unsigned int r = (u + 0x7fffu + ((u >> 16) & 1u)) >> 16;   // RNE
    return (u16)r;
}
__device__ __forceinline__ float bf2f(u16 b) {
    return __uint_as_float(((unsigned int)b) << 16);
}

// async global->LDS, 16B per lane, dest = wave-uniform base + lane*16
__device__ __forceinline__ void gload16(const void* g, void* l) {
    __builtin_amdgcn_global_load_lds(
        (const __attribute__((address_space(1))) unsigned int*)g,
        (__attribute__((address_space(3))) unsigned int*)l,
        16, 0, 0);
}

// Bank-conflict-free plane staging with XOR swizzle.
// Plane = [16 rows x 32 u16] per row-group rg, row-major, but the four 8-u16
// chunks of each row are permuted: LDS slot s holds logical chunk q = s ^ tkey(row),
// tkey(r) = (r&3) ^ ((r>>2)&3).  global_load_lds dst is lane-contiguous (required),
// we permute which global chunk each lane FETCHES instead.
__device__ __forceinline__ void stage_plane(const u16* src_base, int row_stride, int k0,
                                            int rg, int lane, u16* dst) {
    int rl  = lane >> 2;                 // row within group, 0..15
    int row = rg * 16 + rl;
    int q   = (lane & 3) ^ (rl & 3) ^ ((rl >> 2) & 3);
    const u16* s = src_base + (size_t)row * row_stride + k0 + q * 8;
    gload16(s, dst + rg * 512);
}

// ---------------- stats: mean + std(ddof=1) over t, per (b,d) ----------------
__global__ void stats_partial(const float* __restrict__ x,
                              float* __restrict__ part, float* __restrict__ part2) {
    int d  = blockIdx.x * 256 + threadIdx.x;
    int tc = blockIdx.y;
    int b  = blockIdx.z;
    const float* p = x + (size_t)b * T_ * D_ + (size_t)tc * 128 * D_ + d;
    float s = 0.f, s2 = 0.f;
    for (int t = 0; t < 128; ++t) {
        float v = p[(size_t)t * D_];
        s += v; s2 += v * v;
    }
    part [(b * 16 + tc) * D_ + d] = s;
    part2[(b * 16 + tc) * D_ + d] = s2;
}

__global__ void stats_final(const float* __restrict__ part, const float* __restrict__ part2,
                            float* __restrict__ ms) {
    int idx = blockIdx.x * 256 + threadIdx.x;
    if (idx >= B_ * D_) return;
    int b = idx / D_, d = idx % D_;
    float s = 0.f, s2 = 0.f;
    for (int i = 0; i < 16; ++i) {
        s  += part [(b * 16 + i) * D_ + d];
        s2 += part2[(b * 16 + i) * D_ + d];
    }
    float mean = s / (float)T_;
    float var  = (s2 - (float)T_ * mean * mean) / (float)(T_ - 1);
    ms[idx] = mean + sqrtf(fmaxf(var, 0.f));
}

// msd[b][j] = ms[b,:] . w1[j,:] ;  s1[j] = sum_d w1[j][d]
__global__ void msdot(const float* __restrict__ ms, const float* __restrict__ w1,
                      float* __restrict__ msd, float* __restrict__ s1) {
    int b = blockIdx.x, j = threadIdx.x;
    const float* wr = w1 + (size_t)j * D_;
    const float* mr = ms + (size_t)b * D_;
    float am = 0.f, as = 0.f;
    for (int d4 = 0; d4 < D_ / 4; ++d4) {
        float4 w = *(const float4*)(wr + d4 * 4);
        float4 m = *(const float4*)(mr + d4 * 4);
        am += w.x * m.x + w.y * m.y + w.z * m.z + w.w * m.w;
        as += w.x + w.y + w.z + w.w;
    }
    msd[b * 64 + j] = am;
    if (b == 0) s1[j] = as;
}

// ---------------- weight concat -> bf16: Wh[3072][1024] ----------------
__global__ void split_w(const float* __restrict__ qw0, const float* __restrict__ kw0,
                        const float* __restrict__ ww0, const float* __restrict__ qw1,
                        const float* __restrict__ kw1, const float* __restrict__ ww1,
                        const float* __restrict__ qw2, const float* __restrict__ kw2,
                        const float* __restrict__ ww2, const float* __restrict__ w1s,
                        u16* __restrict__ Wh) {
    int row = blockIdx.x;
    int col = threadIdx.x * 4;
    const float* src = nullptr;
    if      (row < 128)  src = qw0 + (size_t)row * D_;
    else if (row < 160)  src = kw0 + (size_t)(row - 128) * D_;
    else if (row < 164)  src = ww0 + (size_t)(row - 160) * D_;
    else if (row < 168)  src = nullptr;
    else if (row < 680)  src = qw1 + (size_t)(row - 168) * D_;
    else if (row < 744)  src = kw1 + (size_t)(row - 680) * D_;
    else if (row < 752)  src = ww1 + (size_t)(row - 744) * D_;
    else if (row < 2800) src = qw2 + (size_t)(row - 752) * D_;
    else if (row < 2928) src = kw2 + (size_t)(row - 2800) * D_;
    else if (row < 2944) src = ww2 + (size_t)(row - 2928) * D_;
    else if (row < 3008) src = w1s + (size_t)(row - 2944) * D_;
    float4 v = src ? *(const float4*)(src + col) : make_float4(0.f, 0.f, 0.f, 0.f);
    ushort4 h;
    h.x = f2bf(v.x); h.y = f2bf(v.y); h.z = f2bf(v.z); h.w = f2bf(v.w);
    *(ushort4*)&Wh[(size_t)row * D_ + col] = h;
}

// ---------------- x -> bf16 ----------------
__global__ void cast_x(const float* __restrict__ x, u16* __restrict__ Xh) {
    size_t i = ((size_t)blockIdx.x * 256 + threadIdx.x) * 4;
    float4 v = *(const float4*)(x + i);
    ushort4 h;
    h.x = f2bf(v.x); h.y = f2bf(v.y); h.z = f2bf(v.z); h.w = f2bf(v.w);
    *(ushort4*)&Xh[i] = h;
}

// ---------------- projection GEMM: Ph[4096,3072] = bf16( Xh @ Wh^T ) ----------------
__global__ __launch_bounds__(256, 4) void proj_gemm(
    const u16* __restrict__ Xh, const u16* __restrict__ Wh, u16* __restrict__ Ph) {
    __shared__ u16 As[2][4096], Bs[2][4096];
    int tid = threadIdx.x;
    int wave = tid >> 6, lane = tid & 63;
    int bm = blockIdx.x * 128, bn = blockIdx.y * 128;
    int wt = wave >> 1, wn = wave & 1;
    int fm = lane & 31, hv = lane >> 5;
    int tkey = (fm & 3) ^ ((fm >> 2) & 3);
    f32x16 acc[2][2];
#pragma unroll
    for (int i = 0; i < 2; ++i)
#pragma unroll
        for (int j = 0; j < 2; ++j)
#pragma unroll
            for (int r = 0; r < 16; ++r) acc[i][j][r] = 0.f;

    const u16* xh = Xh + (size_t)bm * D_;
    const u16* wh = Wh + (size_t)bn * D_;

    auto stage = [&](int buf, int k0) {
#pragma unroll
        for (int i = 0; i < 4; ++i) {
            int j = wave * 4 + i;              // 16 jobs: 2 planes x 8 row-groups
            int pl = j >> 3, rg = j & 7;
            stage_plane(pl ? wh : xh, D_, k0, rg, lane, pl ? Bs[buf] : As[buf]);
        }
    };

    stage(0, 0);
    for (int kc = 0; kc < 32; ++kc) {
        __syncthreads();
        if (kc + 1 < 32) stage((kc + 1) & 1, (kc + 1) * 32);
        const u16* ah = As[kc & 1];
        const u16* bh = Bs[kc & 1];
#pragma unroll
        for (int ks = 0; ks < 2; ++ks) {
            int slot8 = ((ks * 2 + hv) ^ tkey) * 8;
            bf16x8 a_h[2], b_h[2];
#pragma unroll
            for (int t = 0; t < 2; ++t) {
                a_h[t] = *(const bf16x8*)&ah[(wt * 64 + t * 32 + fm) * 32 + slot8];
                b_h[t] = *(const bf16x8*)&bh[(wn * 64 + t * 32 + fm) * 32 + slot8];
            }
#pragma unroll
            for (int ti = 0; ti < 2; ++ti)
#pragma unroll
                for (int tj = 0; tj < 2; ++tj)
                    acc[ti][tj] = __builtin_amdgcn_mfma_f32_32x32x16_bf16(a_h[ti], b_h[tj], acc[ti][tj], 0, 0, 0);
        }
    }
#pragma unroll
    for (int ti = 0; ti < 2; ++ti)
#pragma unroll
        for (int tj = 0; tj < 2; ++tj)
#pragma unroll
            for (int r = 0; r < 16; ++r) {
                int row = bm + wt * 64 + ti * 32 + (r & 3) + 8 * (r >> 2) + 4 * (lane >> 5);
                int col = bn + wn * 64 + tj * 32 + (lane & 31);
                Ph[(size_t)row * LDN + col] = f2bf(acc[ti][tj][r]);
            }
}

// ---------------- selector layers 2-3 + softmax (layer1 from proj GEMM) ----------
__global__ void selector2(const u16* __restrict__ Ph,
                          const float* __restrict__ msd, const float* __restrict__ s1,
                          const float* __restrict__ b1, const float* __restrict__ w2,
                          const float* __restrict__ b2, const float* __restrict__ w3,
                          const float* __restrict__ b3, float* __restrict__ PR) {
    __shared__ float h1s[4][64];
    __shared__ float h2s[4][64];
    __shared__ float lg[4][3];
    int tid = threadIdx.x;
    int slot = tid >> 6, j = tid & 63;
    int bt = blockIdx.x * 4 + slot;
    int b = bt >> 11, t = bt & 2047;
    size_t pidx = (size_t)bt * LDN + SELO + j;
    float v = bf2f(Ph[pidx])
            + msd[b * 64 + j] + 0.1f * ((float)t / (float)T_) * s1[j] + b1[j];
    h1s[slot][j] = fmaxf(v, 0.f);
    __syncthreads();
    float a2 = b2[j];
#pragma unroll 8
    for (int d = 0; d < 64; ++d) a2 = fmaf(h1s[slot][d], w2[j * 64 + d], a2);
    h2s[slot][j] = fmaxf(a2, 0.f);
    __syncthreads();
    if (j < 3) {
        float a3 = b3[j];
        for (int d = 0; d < 64; ++d) a3 = fmaf(h2s[slot][d], w3[j * 64 + d], a3);
        lg[slot][j] = a3;
    }
    __syncthreads();
    if (j == 0) {
        float m = fmaxf(lg[slot][0], fmaxf(lg[slot][1], lg[slot][2]));
        float e0 = expf(lg[slot][0] - m), e1 = expf(lg[slot][1] - m), e2 = expf(lg[slot][2] - m);
        float inv = 1.f / (e0 + e1 + e2);
        PR[bt * 3 + 0] = e0 * inv;
        PR[bt * 3 + 1] = e1 * inv;
        PR[bt * 3 + 2] = e2 * inv;
    }
}

__device__ __forceinline__ int qcol_of(int c) {
    if (c < 2)  return QO0 + c * 64;
    if (c < 10) return QO1 + (c - 2) * 64;
    int u = c - 10;
    return QO2 + (u >> 1) * 128 + (u & 1) * 64;
}

// ---------------- fused relu-attention score kernel (bf16 MFMA, K-resident) ----------------
__global__ __launch_bounds__(256, 2) void score_kernel(
    const u16* __restrict__ Ph, const float* __restrict__ PR, float* __restrict__ out) {
    __shared__ u16 Qs[2][8192];    // 2 bufs x 2 planes x [128][32]
    __shared__ u16 Ks[4 * 4096];   // up to 4 planes x [128][32]
    __shared__ float wpT[28 * 128];
    int tid = threadIdx.x;
    int wave = tid >> 6, lane = tid & 63;
    int wt = wave >> 1, wn = wave & 1;
    int fm = lane & 31, hv = lane >> 5;
    int tkey = (fm & 3) ^ ((fm >> 2) & 3);

    // XCD-aware swizzle: keep blocks sharing a Q-tile (same b,t0) on one XCD
    int n = blockIdx.z * 256 + blockIdx.y * 16 + blockIdx.x;
    int p = (n & 7) * 4 + (n >> 7);
    int xb = (n >> 3) & 15;
    int b = p >> 4, yb = p & 15;
    int t0 = yb * 128, s0 = xb * 128;

    const u16* Pq = Ph + (size_t)(b * T_ + t0) * LDN;  // Q rows
    const u16* Pk = Ph + (size_t)(b * T_ + s0) * LDN;  // K rows

    auto stageQ = [&](int buf, int qcol) {
#pragma unroll
        for (int i = 0; i < 4; ++i) {
            int j = (wave << 2) + i;
            int pl = j >> 3, rg = j & 7;
            stage_plane(Pq, LDN, qcol + pl * 32, rg, lane, &Qs[buf][pl * 4096]);
        }
    };
    auto stageK = [&](int kbase, int nplanes) {
        for (int j = wave; j < nplanes * 8; j += 4) {
            int pl = j >> 3, rg = j & 7;
            stage_plane(Pk, LDN, kbase + pl * 32, rg, lane, &Ks[pl * 4096]);
        }
    };

    // prologue staging: K for cfg0 + Q chunk 0
    stageK(KO0, 1);
    stageQ(0, qcol_of(0));

    // wp transposed: wpT[g][row] = w_g(row) * prob_cfg(row)
    for (int idx = tid; idx < 28 * 128; idx += 256) {
        int g = idx >> 7, r = idx & 127;
        int wcol = (g < 4) ? (WO0 + g) : ((g < 12) ? (WO1 + g - 4) : (WO2 + g - 12));
        int cfg  = (g < 4) ? 0 : ((g < 12) ? 1 : 2);
        size_t prow = (size_t)(b * T_ + t0 + r);
        wpT[g * 128 + r] = bf2f(Ph[prow * LDN + wcol]) * PR[prow * 3 + cfg];
    }

    f32x16 outacc[2][2], dots[2][2];
#pragma unroll
    for (int i = 0; i < 2; ++i)
#pragma unroll
        for (int j = 0; j < 2; ++j)
#pragma unroll
            for (int r = 0; r < 16; ++r) { outacc[i][j][r] = 0.f; dots[i][j][r] = 0.f; }

    for (int c = 0; c < 42; ++c) {
        int kp0, kp1, gMid, gEnd;
        if (c < 2)       { kp0 = 0; kp1 = 0; gMid = 2 * c; gEnd = 2 * c + 1; }
        else if (c < 10) { kp0 = 0; kp1 = 1; gMid = -1; gEnd = 4 + (c - 2); }
        else { int u = c - 10; int h = u >> 1, kb = u & 1;
               kp0 = kb * 2; kp1 = kb * 2 + 1; gMid = -1; gEnd = kb ? (12 + h) : -1; }

        __syncthreads();   // staged data (Q[c], K for this cfg, wpT on c==0) ready
        if (c < 41) stageQ((c + 1) & 1, qcol_of(c + 1));   // overlap with compute below

        const u16* qb = Qs[c & 1];
#pragma unroll
        for (int ks = 0; ks < 4; ++ks) {
            int slot8 = (((ks & 1) * 2 + hv) ^ tkey) * 8;
            int kp = (ks < 2) ? kp0 : kp1;
            bf16x8 kf[2], qf[2];
#pragma unroll
            for (int tj = 0; tj < 2; ++tj)
                kf[tj] = *(const bf16x8*)&Ks[kp * 4096 + (wn * 64 + tj * 32 + fm) * 32 + slot8];
#pragma unroll
            for (int ti = 0; ti < 2; ++ti)
                qf[ti] = *(const bf16x8*)&qb[(ks >> 1) * 4096 + (wt * 64 + ti * 32 + fm) * 32 + slot8];
#pragma unroll
            for (int ti = 0; ti < 2; ++ti)
#pragma unroll
                for (int tj = 0; tj < 2; ++tj)
                    dots[ti][tj] = __builtin_amdgcn_mfma_f32_32x32x16_bf16(qf[ti], kf[tj], dots[ti][tj], 0, 0, 0);

            int g = (ks == 1) ? gMid : ((ks == 3) ? gEnd : -1);
            if (g >= 0) {
#pragma unroll
                for (int ti = 0; ti < 2; ++ti) {
                    int rowbase = wt * 64 + ti * 32 + 4 * (lane >> 5);
#pragma unroll
                    for (int rq = 0; rq < 4; ++rq) {
                        float4 w4 = *(const float4*)&wpT[g * 128 + rowbase + rq * 8];
                        float wv[4] = {w4.x, w4.y, w4.z, w4.w};
#pragma unroll
                        for (int tj = 0; tj < 2; ++tj)
#pragma unroll
                            for (int r2 = 0; r2 < 4; ++r2) {
                                int r = rq * 4 + r2;
                                outacc[ti][tj][r] += fmaxf(dots[ti][tj][r], 0.f) * wv[r2];
                                dots[ti][tj][r] = 0.f;
                            }
                    }
                }
            }
        }
        // cfg boundaries: all waves must finish reading Ks before restage
        if (c == 1)      { __syncthreads(); stageK(KO1, 2); }
        else if (c == 9) { __syncthreads(); stageK(KO2, 4); }
    }

#pragma unroll
    for (int ti = 0; ti < 2; ++ti)
#pragma unroll
        for (int tj = 0; tj < 2; ++tj)
#pragma unroll
            for (int r = 0; r < 16; ++r) {
                int trow = wt * 64 + ti * 32 + (r & 3) + 8 * (r >> 2) + 4 * (lane >> 5);
                int scol = wn * 64 + tj * 32 + (lane & 31);
                out[(size_t)(b * T_ + t0 + trow) * T_ + (s0 + scol)] = outacc[ti][tj][r];
            }
}

extern "C" void kernel_launch(void* const* d_in, const int* in_sizes, int n_in,
                              void* d_out, int out_size, void* d_ws, size_t ws_size,
                              hipStream_t stream) {
    const float* x   = (const float*)d_in[0];
    const float* w1  = (const float*)d_in[1];
    const float* b1  = (const float*)d_in[2];
    const float* w2  = (const float*)d_in[3];
    const float* b2  = (const float*)d_in[4];
    const float* w3  = (const float*)d_in[5];
    const float* b3  = (const float*)d_in[6];
    const float* qw0 = (const float*)d_in[7];
    const float* kw0 = (const float*)d_in[8];
    const float* ww0 = (const float*)d_in[9];
    const float* qw1 = (const float*)d_in[10];
    const float* kw1 = (const float*)d_in[11];
    const float* ww1 = (const float*)d_in[12];
    const float* qw2 = (const float*)d_in[13];
    const float* kw2 = (const float*)d_in[14];
    const float* ww2 = (const float*)d_in[15];
    float* out = (float*)d_out;

    // workspace carve-up: ~40 MB total
    float* fb = (float*)d_ws;
    float* MS  = fb; fb += 2048;
    float* MSD = fb; fb += 128;
    float* S1  = fb; fb += 64;
    float* PR  = fb; fb += (size_t)M_ * 3;
    float* PA  = fb; fb += (size_t)B_ * 16 * D_;
    float* PA2 = fb; fb += (size_t)B_ * 16 * D_;
    u16* ub = (u16*)fb;
    u16* Wh = ub; ub += (size_t)LDN * D_;      // 6.3 MB
    u16* Xh = ub; ub += (size_t)M_ * D_;       // 8 MB
    u16* Ph = ub; ub += (size_t)M_ * LDN;      // 25 MB

    stats_partial<<<dim3(D_ / 256, 16, B_), 256, 0, stream>>>(x, PA, PA2);
    stats_final<<<dim3((B_ * D_ + 255) / 256), 256, 0, stream>>>(PA, PA2, MS);
    msdot<<<dim3(B_), 64, 0, stream>>>(MS, w1, MSD, S1);
    split_w<<<dim3(LDN), 256, 0, stream>>>(qw0, kw0, ww0, qw1, kw1, ww1,
                                           qw2, kw2, ww2, w1, Wh);
    cast_x<<<dim3((M_ * D_) / 1024), 256, 0, stream>>>(x, Xh);
    proj_gemm<<<dim3(M_ / 128, LDN / 128), 256, 0, stream>>>(Xh, Wh, Ph);
    selector2<<<dim3(M_ / 4), 256, 0, stream>>>(Ph, MSD, S1, b1, w2, b2, w3, b3, PR);
    score_kernel<<<dim3(T_ / 128, T_ / 128, B_), 256, 0, stream>>>(Ph, PR, out);
}

// Round 5
// 269.299 us; speedup vs baseline: 5.9154x; 1.0155x over previous
//
#include <hip/hip_runtime.h>
#include <hip/hip_fp16.h>
#include <cstdint>
#include <cstddef>
#include <math.h>

#define B_ 2
#define T_ 2048
#define D_ 1024
#define M_ (B_*T_)

// column layout of P (= row layout of W concat), all offsets multiples of 8
#define QO0 0
#define KO0 128
#define WO0 160
#define QO1 168
#define KO1 680
#define WO1 744
#define QO2 752
#define KO2 2800
#define WO2 2928
#define SELO 2944
#define LDN 3072

typedef float f32x16 __attribute__((ext_vector_type(16)));
typedef short bf16x8 __attribute__((ext_vector_type(8)));
typedef unsigned short u16;

__device__ __forceinline__ u16 f2bf(float f) {
    unsigned int u = __float_as_uint(f);
    unsigned int r = (u + 0x7fffu + ((u >> 16) & 1u)) >> 16;   // RNE
    return (u16)r;
}
__device__ __forceinline__ float bf2f(u16 b) {
    return __uint_as_float(((unsigned int)b) << 16);
}

// async global->LDS, 16B per lane, dest = wave-uniform base + lane*16
__device__ __forceinline__ void gload16(const void* g, void* l) {
    __builtin_amdgcn_global_load_lds(
        (const __attribute__((address_space(1))) unsigned int*)g,
        (__attribute__((address_space(3))) unsigned int*)l,
        16, 0, 0);
}

// Bank-conflict-free 16row x 32col u16 plane-slice staging with XOR swizzle.
// LDS slot s of row r holds logical 8-u16 chunk s ^ tkey(r), tkey(r) = (r&3)^((r>>2)&3).
__device__ __forceinline__ void stage_plane(const u16* src_base, int row_stride, int k0,
                                            int rg, int lane, u16* dst) {
    int rl  = lane >> 2;
    int row = rg * 16 + rl;
    int q   = (lane & 3) ^ (rl & 3) ^ ((rl >> 2) & 3);
    const u16* s = src_base + (size_t)row * row_stride + k0 + q * 8;
    gload16(s, dst + rg * 512);
}

// ---------------- pass 1: partial sums over t + x -> bf16 cast ----------------
__global__ void stats1(const float* __restrict__ x, float* __restrict__ part,
                       float* __restrict__ part2, u16* __restrict__ Xh) {
    int d  = blockIdx.x * 256 + threadIdx.x;
    int tc = blockIdx.y;
    int b  = blockIdx.z;
    size_t base = (size_t)b * T_ * D_ + (size_t)tc * 128 * D_ + d;
    float s = 0.f, s2 = 0.f;
    for (int t = 0; t < 128; ++t) {
        float v = x[base + (size_t)t * D_];
        s += v; s2 += v * v;
        Xh[base + (size_t)t * D_] = f2bf(v);
    }
    part [(b * 16 + tc) * D_ + d] = s;
    part2[(b * 16 + tc) * D_ + d] = s2;
}

// ---------------- pass 2: finalize mean+std, fold msd & s1 ----------------
__global__ void stats2(const float* __restrict__ part, const float* __restrict__ part2,
                       const float* __restrict__ w1,
                       float* __restrict__ msd, float* __restrict__ s1) {
    __shared__ float msL[1024];
    __shared__ float ps[64][17];
    __shared__ float pw[64][17];
    int b = blockIdx.x, tid = threadIdx.x;
    float s = 0.f, s2 = 0.f;
    for (int i = 0; i < 16; ++i) {
        s  += part [(b * 16 + i) * D_ + tid];
        s2 += part2[(b * 16 + i) * D_ + tid];
    }
    float mean = s / (float)T_;
    float var  = (s2 - (float)T_ * mean * mean) / (float)(T_ - 1);
    msL[tid] = mean + sqrtf(fmaxf(var, 0.f));
    __syncthreads();
    int j = tid >> 4, cc = tid & 15;
    float am = 0.f, aw = 0.f;
    const float* wr = w1 + (size_t)j * D_ + cc * 64;
    const float* mr = msL + cc * 64;
    for (int dd = 0; dd < 64; ++dd) { float w = wr[dd]; am += mr[dd] * w; aw += w; }
    ps[j][cc] = am; pw[j][cc] = aw;
    __syncthreads();
    if (tid < 64) {
        float sm = 0.f, sw = 0.f;
        for (int i = 0; i < 16; ++i) { sm += ps[tid][i]; sw += pw[tid][i]; }
        msd[b * 64 + tid] = sm;
        if (b == 0) s1[tid] = sw;
    }
}

// ---------------- weight concat -> bf16: Wh[3072][1024] ----------------
__global__ void split_w(const float* __restrict__ qw0, const float* __restrict__ kw0,
                        const float* __restrict__ ww0, const float* __restrict__ qw1,
                        const float* __restrict__ kw1, const float* __restrict__ ww1,
                        const float* __restrict__ qw2, const float* __restrict__ kw2,
                        const float* __restrict__ ww2, const float* __restrict__ w1s,
                        u16* __restrict__ Wh) {
    int row = blockIdx.x;
    int col = threadIdx.x * 4;
    const float* src = nullptr;
    if      (row < 128)  src = qw0 + (size_t)row * D_;
    else if (row < 160)  src = kw0 + (size_t)(row - 128) * D_;
    else if (row < 164)  src = ww0 + (size_t)(row - 160) * D_;
    else if (row < 168)  src = nullptr;
    else if (row < 680)  src = qw1 + (size_t)(row - 168) * D_;
    else if (row < 744)  src = kw1 + (size_t)(row - 680) * D_;
    else if (row < 752)  src = ww1 + (size_t)(row - 744) * D_;
    else if (row < 2800) src = qw2 + (size_t)(row - 752) * D_;
    else if (row < 2928) src = kw2 + (size_t)(row - 2800) * D_;
    else if (row < 2944) src = ww2 + (size_t)(row - 2928) * D_;
    else if (row < 3008) src = w1s + (size_t)(row - 2944) * D_;
    float4 v = src ? *(const float4*)(src + col) : make_float4(0.f, 0.f, 0.f, 0.f);
    ushort4 h;
    h.x = f2bf(v.x); h.y = f2bf(v.y); h.z = f2bf(v.z); h.w = f2bf(v.w);
    *(ushort4*)&Wh[(size_t)row * D_ + col] = h;
}

// ---------------- projection GEMM: Ph[4096,3072] = bf16( Xh @ Wh^T ) ----------------
__global__ __launch_bounds__(256, 4) void proj_gemm(
    const u16* __restrict__ Xh, const u16* __restrict__ Wh, u16* __restrict__ Ph) {
    __shared__ u16 As[2][4096], Bs[2][4096];
    int tid = threadIdx.x;
    int wave = tid >> 6, lane = tid & 63;
    int bm = blockIdx.x * 128, bn = blockIdx.y * 128;
    int wt = wave >> 1, wn = wave & 1;
    int fm = lane & 31, hv = lane >> 5;
    int tkey = (fm & 3) ^ ((fm >> 2) & 3);
    f32x16 acc[2][2];
#pragma unroll
    for (int i = 0; i < 2; ++i)
#pragma unroll
        for (int j = 0; j < 2; ++j)
#pragma unroll
            for (int r = 0; r < 16; ++r) acc[i][j][r] = 0.f;

    const u16* xh = Xh + (size_t)bm * D_;
    const u16* wh = Wh + (size_t)bn * D_;

    auto stage = [&](int buf, int k0) {
#pragma unroll
        for (int i = 0; i < 4; ++i) {
            int j = wave * 4 + i;
            int pl = j >> 3, rg = j & 7;
            stage_plane(pl ? wh : xh, D_, k0, rg, lane, pl ? Bs[buf] : As[buf]);
        }
    };

    stage(0, 0);
    for (int kc = 0; kc < 32; ++kc) {
        __syncthreads();
        if (kc + 1 < 32) stage((kc + 1) & 1, (kc + 1) * 32);
        const u16* ah = As[kc & 1];
        const u16* bh = Bs[kc & 1];
#pragma unroll
        for (int ks = 0; ks < 2; ++ks) {
            int slot8 = ((ks * 2 + hv) ^ tkey) * 8;
            bf16x8 a_h[2], b_h[2];
#pragma unroll
            for (int t = 0; t < 2; ++t) {
                a_h[t] = *(const bf16x8*)&ah[(wt * 64 + t * 32 + fm) * 32 + slot8];
                b_h[t] = *(const bf16x8*)&bh[(wn * 64 + t * 32 + fm) * 32 + slot8];
            }
#pragma unroll
            for (int ti = 0; ti < 2; ++ti)
#pragma unroll
                for (int tj = 0; tj < 2; ++tj)
                    acc[ti][tj] = __builtin_amdgcn_mfma_f32_32x32x16_bf16(a_h[ti], b_h[tj], acc[ti][tj], 0, 0, 0);
        }
    }
#pragma unroll
    for (int ti = 0; ti < 2; ++ti)
#pragma unroll
        for (int tj = 0; tj < 2; ++tj)
#pragma unroll
            for (int r = 0; r < 16; ++r) {
                int row = bm + wt * 64 + ti * 32 + (r & 3) + 8 * (r >> 2) + 4 * (lane >> 5);
                int col = bn + wn * 64 + tj * 32 + (lane & 31);
                Ph[(size_t)row * LDN + col] = f2bf(acc[ti][tj][r]);
            }
}

// ---------------- selector layers 2-3 + softmax + WP=w*prob (f16) ----------
__global__ void selector2(const u16* __restrict__ Ph,
                          const float* __restrict__ msd, const float* __restrict__ s1,
                          const float* __restrict__ b1, const float* __restrict__ w2,
                          const float* __restrict__ b2, const float* __restrict__ w3,
                          const float* __restrict__ b3, __half* __restrict__ WP) {
    __shared__ float h1s[4][64];
    __shared__ float h2s[4][64];
    __shared__ float lg[4][3];
    int tid = threadIdx.x;
    int slot = tid >> 6, j = tid & 63;
    int bt = blockIdx.x * 4 + slot;
    int b = bt >> 11, t = bt & 2047;
    size_t pidx = (size_t)bt * LDN + SELO + j;
    float v = bf2f(Ph[pidx])
            + msd[b * 64 + j] + 0.1f * ((float)t / (float)T_) * s1[j] + b1[j];
    h1s[slot][j] = fmaxf(v, 0.f);
    __syncthreads();
    float a2 = b2[j];
#pragma unroll 8
    for (int d = 0; d < 64; ++d) a2 = fmaf(h1s[slot][d], w2[j * 64 + d], a2);
    h2s[slot][j] = fmaxf(a2, 0.f);
    __syncthreads();
    if (j < 3) {
        float a3 = b3[j];
        for (int d = 0; d < 64; ++d) a3 = fmaf(h2s[slot][d], w3[j * 64 + d], a3);
        lg[slot][j] = a3;
    }
    __syncthreads();
    if (j < 28) {
        float m = fmaxf(lg[slot][0], fmaxf(lg[slot][1], lg[slot][2]));
        float e0 = expf(lg[slot][0] - m), e1 = expf(lg[slot][1] - m), e2 = expf(lg[slot][2] - m);
        float inv = 1.f / (e0 + e1 + e2);
        int wcol = (j < 4) ? (WO0 + j) : ((j < 12) ? (WO1 + j - 4) : (WO2 + j - 12));
        float p = ((j < 4) ? e0 : ((j < 12) ? e1 : e2)) * inv;
        float w = bf2f(Ph[(size_t)bt * LDN + wcol]);
        WP[(size_t)(b * 28 + j) * T_ + t] = __float2half(w * p);
    }
}

// ---------------- fused relu-attention score kernel (high occupancy) ----------------
// block tile 128(t) x 64(s), 4 waves of 64x32, 4 blocks/CU
__global__ __launch_bounds__(256, 4) void score_kernel(
    const u16* __restrict__ Ph, const __half* __restrict__ WP, float* __restrict__ out) {
    __shared__ u16 Qs[2][4096];     // dbuf: 128 t-rows x 32 cols
    __shared__ u16 Ks[4][2048];     // 4 planes: 64 s-rows x 32 cols
    __shared__ __half wpL[3584];    // [28][128]
    int tid = threadIdx.x;
    int wave = tid >> 6, lane = tid & 63;
    int wt = wave >> 1, wn = wave & 1;
    int fm = lane & 31, hv = lane >> 5;
    int tkey = (fm & 3) ^ ((fm >> 2) & 3);

    // XCD-aware decode: blocks with same (n&7) land on one XCD; give each XCD 4 Q-tiles
    int n = blockIdx.x;
    int qt = (n & 7) * 4 + (n >> 8);        // 0..31: (b, t-tile)
    int b = qt >> 4, t0 = (qt & 15) * 128;
    int s0 = ((n >> 3) & 31) * 64;

    const u16* Pq = Ph + (size_t)(b * T_ + t0) * LDN;
    const u16* Pk = Ph + (size_t)(b * T_ + s0) * LDN;

    auto stageQ = [&](int buf, int qcol) {
#pragma unroll
        for (int i = 0; i < 2; ++i) {
            int rg = wave * 2 + i;
            stage_plane(Pq, LDN, qcol, rg, lane, Qs[buf]);
        }
    };

    // prologue: K planes for cfg0 (1) + cfg1 (2); wp slice; Q chunk 0
#pragma unroll
    for (int i = 0; i < 3; ++i) {
        int j = i * 4 + wave;
        int pl = j >> 2, rg = j & 3;
        int col = (pl == 0) ? KO0 : ((pl == 1) ? KO1 : KO1 + 32);
        stage_plane(Pk, LDN, col, rg, lane, Ks[pl]);
    }
#pragma unroll
    for (int i = 0; i < 2; ++i) {
        int j = i * 4 + wave;
        if (j < 7) {
            const __half* src = WP + (size_t)(b * 28 + j * 4 + (lane >> 4)) * T_ + t0 + (lane & 15) * 8;
            gload16(src, (u16*)wpL + j * 512);
        }
    }
    stageQ(0, QO0);

    f32x16 outacc[2], dots[2];
#pragma unroll
    for (int i = 0; i < 2; ++i)
#pragma unroll
        for (int r = 0; r < 16; ++r) { outacc[i][r] = 0.f; dots[i][r] = 0.f; }

    for (int c = 0; c < 84; ++c) {
        int kp, g;
        if (c < 4)       { kp = 0; g = c; }
        else if (c < 20) { int u = c - 4;  kp = 1 + (u & 1); g = (u & 1) ? (4 + (u >> 1)) : -1; }
        else             { int u = c - 20; kp = u & 3; g = ((u & 3) == 3) ? (12 + (u >> 2)) : -1; }

        __syncthreads();   // staged Q[c] (+K/wp on c==0, K-cfg2 on c==20) ready
        if (c < 83) {
            int nc = c + 1;
            int nq = (nc < 4) ? (QO0 + nc * 32)
                   : ((nc < 20) ? (QO1 + (nc - 4) * 32) : (QO2 + (nc - 20) * 32));
            stageQ((nc) & 1, nq);
        }

        const u16* qb = Qs[c & 1];
        const u16* kb = Ks[kp];
#pragma unroll
        for (int ks = 0; ks < 2; ++ks) {
            int slot8 = ((ks * 2 + hv) ^ tkey) * 8;
            bf16x8 kf = *(const bf16x8*)&kb[(wn * 32 + fm) * 32 + slot8];
#pragma unroll
            for (int ti = 0; ti < 2; ++ti) {
                bf16x8 qf = *(const bf16x8*)&qb[(wt * 64 + ti * 32 + fm) * 32 + slot8];
                dots[ti] = __builtin_amdgcn_mfma_f32_32x32x16_bf16(qf, kf, dots[ti], 0, 0, 0);
            }
        }

        if (g >= 0) {
#pragma unroll
            for (int ti = 0; ti < 2; ++ti) {
                int rowbase = wt * 64 + ti * 32 + 4 * hv;
#pragma unroll
                for (int rq = 0; rq < 4; ++rq) {
                    const __half2* wp2 = (const __half2*)&wpL[g * 128 + rowbase + rq * 8];
                    float2 f01 = __half22float2(wp2[0]);
                    float2 f23 = __half22float2(wp2[1]);
                    float wv[4] = {f01.x, f01.y, f23.x, f23.y};
#pragma unroll
                    for (int r2 = 0; r2 < 4; ++r2) {
                        int r = rq * 4 + r2;
                        outacc[ti][r] += fmaxf(dots[ti][r], 0.f) * wv[r2];
                        dots[ti][r] = 0.f;
                    }
                }
            }
        }

        if (c == 19) {
            __syncthreads();   // all waves done reading cfg0/cfg1 K planes
#pragma unroll
            for (int i = 0; i < 4; ++i) {
                int j = i * 4 + wave;
                int pl = j >> 2, rg = j & 3;
                stage_plane(Pk, LDN, KO2 + pl * 32, rg, lane, Ks[pl]);
            }
        }
    }

#pragma unroll
    for (int ti = 0; ti < 2; ++ti)
#pragma unroll
        for (int r = 0; r < 16; ++r) {
            int row = wt * 64 + ti * 32 + (r & 3) + 8 * (r >> 2) + 4 * hv;
            out[(size_t)(b * T_ + t0 + row) * T_ + s0 + wn * 32 + fm] = outacc[ti][r];
        }
}

extern "C" void kernel_launch(void* const* d_in, const int* in_sizes, int n_in,
                              void* d_out, int out_size, void* d_ws, size_t ws_size,
                              hipStream_t stream) {
    const float* x   = (const float*)d_in[0];
    const float* w1  = (const float*)d_in[1];
    const float* b1  = (const float*)d_in[2];
    const float* w2  = (const float*)d_in[3];
    const float* b2  = (const float*)d_in[4];
    const float* w3  = (const float*)d_in[5];
    const float* b3  = (const float*)d_in[6];
    const float* qw0 = (const float*)d_in[7];
    const float* kw0 = (const float*)d_in[8];
    const float* ww0 = (const float*)d_in[9];
    const float* qw1 = (const float*)d_in[10];
    const float* kw1 = (const float*)d_in[11];
    const float* ww1 = (const float*)d_in[12];
    const float* qw2 = (const float*)d_in[13];
    const float* kw2 = (const float*)d_in[14];
    const float* ww2 = (const float*)d_in[15];
    float* out = (float*)d_out;

    // workspace carve-up: ~40 MB
    float* fb = (float*)d_ws;
    float* PA  = fb; fb += (size_t)B_ * 16 * D_;
    float* PA2 = fb; fb += (size_t)B_ * 16 * D_;
    float* MSD = fb; fb += 128;
    float* S1  = fb; fb += 64;
    __half* WP = (__half*)fb; fb += (size_t)B_ * 28 * T_ / 2;
    u16* ub = (u16*)fb;
    u16* Wh = ub; ub += (size_t)LDN * D_;      // 6.3 MB
    u16* Xh = ub; ub += (size_t)M_ * D_;       // 8 MB
    u16* Ph = ub; ub += (size_t)M_ * LDN;      // 25 MB

    stats1<<<dim3(D_ / 256, 16, B_), 256, 0, stream>>>(x, PA, PA2, Xh);
    stats2<<<dim3(B_), 1024, 0, stream>>>(PA, PA2, w1, MSD, S1);
    split_w<<<dim3(LDN), 256, 0, stream>>>(qw0, kw0, ww0, qw1, kw1, ww1,
                                           qw2, kw2, ww2, w1, Wh);
    proj_gemm<<<dim3(M_ / 128, LDN / 128), 256, 0, stream>>>(Xh, Wh, Ph);
    selector2<<<dim3(M_ / 4), 256, 0, stream>>>(Ph, MSD, S1, b1, w2, b2, w3, b3, WP);
    score_kernel<<<dim3(1024), 256, 0, stream>>>(Ph, WP, out);
}

// Round 7
// 256.768 us; speedup vs baseline: 6.2041x; 1.0488x over previous
//
#include <hip/hip_runtime.h>
#include <hip/hip_fp16.h>
#include <cstdint>
#include <cstddef>
#include <math.h>

#define B_ 2
#define T_ 2048
#define D_ 1024
#define M_ (B_*T_)

// column layout of P (= row layout of W concat), all offsets multiples of 8
#define QO0 0
#define KO0 128
#define WO0 160
#define QO1 168
#define KO1 680
#define WO1 744
#define QO2 752
#define KO2 2800
#define WO2 2928
#define SELO 2944
#define LDN 3072

typedef float f32x16 __attribute__((ext_vector_type(16)));
typedef short bf16x8 __attribute__((ext_vector_type(8)));
typedef unsigned short u16;

__device__ __forceinline__ u16 f2bf(float f) {
    unsigned int u = __float_as_uint(f);
    unsigned int r = (u + 0x7fffu + ((u >> 16) & 1u)) >> 16;   // RNE
    return (u16)r;
}
__device__ __forceinline__ float bf2f(u16 b) {
    return __uint_as_float(((unsigned int)b) << 16);
}

// async global->LDS, 16B per lane, dest = wave-uniform base + lane*16
__device__ __forceinline__ void gload16(const void* g, void* l) {
    __builtin_amdgcn_global_load_lds(
        (const __attribute__((address_space(1))) unsigned int*)g,
        (__attribute__((address_space(3))) unsigned int*)l,
        16, 0, 0);
}

// Bank-conflict-free 16row x 32col u16 plane-slice staging with XOR swizzle.
// LDS slot s of row r holds logical 8-u16 chunk s ^ tkey(r), tkey(r) = (r&3)^((r>>2)&3).
__device__ __forceinline__ void stage_plane(const u16* src_base, int row_stride, int k0,
                                            int rg, int lane, u16* dst) {
    int rl  = lane >> 2;
    int row = rg * 16 + rl;
    int q   = (lane & 3) ^ (rl & 3) ^ ((rl >> 2) & 3);
    const u16* s = src_base + (size_t)row * row_stride + k0 + q * 8;
    gload16(s, dst + rg * 512);
}

// ---------------- pass 1: partial sums over t (16-row chunks) + x -> bf16 ----------------
__global__ void stats1(const float* __restrict__ x, float* __restrict__ part,
                       float* __restrict__ part2, u16* __restrict__ Xh) {
    int d  = blockIdx.x * 256 + threadIdx.x;
    int tc = blockIdx.y;                       // 0..127
    int b  = blockIdx.z;
    size_t base = (size_t)b * T_ * D_ + (size_t)tc * 16 * D_ + d;
    float s = 0.f, s2 = 0.f;
#pragma unroll
    for (int t = 0; t < 16; ++t) {
        float v = x[base + (size_t)t * D_];
        s += v; s2 += v * v;
        Xh[base + (size_t)t * D_] = f2bf(v);
    }
    part [(b * 128 + tc) * D_ + d] = s;
    part2[(b * 128 + tc) * D_ + d] = s2;
}

// ---------------- pass 2: finalize mean+std, fold msd & s1 ----------------
__global__ void stats2(const float* __restrict__ part, const float* __restrict__ part2,
                       const float* __restrict__ w1,
                       float* __restrict__ msd, float* __restrict__ s1) {
    __shared__ float msL[1024];
    __shared__ float ps[64][17];
    __shared__ float pw[64][17];
    int b = blockIdx.x, tid = threadIdx.x;
    float s = 0.f, s2 = 0.f;
#pragma unroll 8
    for (int i = 0; i < 128; ++i) {
        s  += part [(b * 128 + i) * D_ + tid];
        s2 += part2[(b * 128 + i) * D_ + tid];
    }
    float mean = s / (float)T_;
    float var  = (s2 - (float)T_ * mean * mean) / (float)(T_ - 1);
    msL[tid] = mean + sqrtf(fmaxf(var, 0.f));
    __syncthreads();
    int j = tid >> 4, cc = tid & 15;
    float am = 0.f, aw = 0.f;
    const float* wr = w1 + (size_t)j * D_ + cc * 64;
    const float* mr = msL + cc * 64;
    for (int dd = 0; dd < 64; ++dd) { float w = wr[dd]; am += mr[dd] * w; aw += w; }
    ps[j][cc] = am; pw[j][cc] = aw;
    __syncthreads();
    if (tid < 64) {
        float sm = 0.f, sw = 0.f;
        for (int i = 0; i < 16; ++i) { sm += ps[tid][i]; sw += pw[tid][i]; }
        msd[b * 64 + tid] = sm;
        if (b == 0) s1[tid] = sw;
    }
}

// ---------------- weight concat -> bf16: Wh[3072][1024] ----------------
__global__ void split_w(const float* __restrict__ qw0, const float* __restrict__ kw0,
                        const float* __restrict__ ww0, const float* __restrict__ qw1,
                        const float* __restrict__ kw1, const float* __restrict__ ww1,
                        const float* __restrict__ qw2, const float* __restrict__ kw2,
                        const float* __restrict__ ww2, const float* __restrict__ w1s,
                        u16* __restrict__ Wh) {
    int row = blockIdx.x;
    int col = threadIdx.x * 4;
    const float* src = nullptr;
    if      (row < 128)  src = qw0 + (size_t)row * D_;
    else if (row < 160)  src = kw0 + (size_t)(row - 128) * D_;
    else if (row < 164)  src = ww0 + (size_t)(row - 160) * D_;
    else if (row < 168)  src = nullptr;
    else if (row < 680)  src = qw1 + (size_t)(row - 168) * D_;
    else if (row < 744)  src = kw1 + (size_t)(row - 680) * D_;
    else if (row < 752)  src = ww1 + (size_t)(row - 744) * D_;
    else if (row < 2800) src = qw2 + (size_t)(row - 752) * D_;
    else if (row < 2928) src = kw2 + (size_t)(row - 2800) * D_;
    else if (row < 2944) src = ww2 + (size_t)(row - 2928) * D_;
    else if (row < 3008) src = w1s + (size_t)(row - 2944) * D_;
    float4 v = src ? *(const float4*)(src + col) : make_float4(0.f, 0.f, 0.f, 0.f);
    ushort4 h;
    h.x = f2bf(v.x); h.y = f2bf(v.y); h.z = f2bf(v.z); h.w = f2bf(v.w);
    *(ushort4*)&Wh[(size_t)row * D_ + col] = h;
}

// ---------------- projection GEMM, m97-style: BK=64 single-buffered ----------------
__global__ __launch_bounds__(256, 3) void proj_gemm(
    const u16* __restrict__ Xh, const u16* __restrict__ Wh, u16* __restrict__ Ph) {
    __shared__ u16 As[8192], Bs[8192];   // 128 rows x 64 cols (2 planes of 32)
    int tid = threadIdx.x;
    int wave = tid >> 6, lane = tid & 63;
    int bm = blockIdx.x * 128, bn = blockIdx.y * 128;
    int wt = wave >> 1, wn = wave & 1;
    int fm = lane & 31, hv = lane >> 5;
    int tkey = (fm & 3) ^ ((fm >> 2) & 3);
    f32x16 acc[2][2];
#pragma unroll
    for (int i = 0; i < 2; ++i)
#pragma unroll
        for (int j = 0; j < 2; ++j)
#pragma unroll
            for (int r = 0; r < 16; ++r) acc[i][j][r] = 0.f;

    const u16* xh = Xh + (size_t)bm * D_;
    const u16* wh = Wh + (size_t)bn * D_;

    for (int kc = 0; kc < 16; ++kc) {
        int k0 = kc * 64;
        // 32 staging jobs: {A,B} x {2 planes} x {8 row-groups}, 8 per wave
#pragma unroll
        for (int i = 0; i < 8; ++i) {
            int j = wave * 8 + i;
            int mat = j >> 4;
            int pl  = (j >> 3) & 1;
            int rg  = j & 7;
            stage_plane(mat ? wh : xh, D_, k0 + pl * 32, rg, lane,
                        (mat ? Bs : As) + pl * 4096);
        }
        __syncthreads();
#pragma unroll
        for (int ks = 0; ks < 4; ++ks) {
            int pl = ks >> 1;
            int slot8 = (((ks & 1) * 2 + hv) ^ tkey) * 8;
            bf16x8 a_h[2], b_h[2];
#pragma unroll
            for (int t = 0; t < 2; ++t) {
                a_h[t] = *(const bf16x8*)&As[pl * 4096 + (wt * 64 + t * 32 + fm) * 32 + slot8];
                b_h[t] = *(const bf16x8*)&Bs[pl * 4096 + (wn * 64 + t * 32 + fm) * 32 + slot8];
            }
#pragma unroll
            for (int ti = 0; ti < 2; ++ti)
#pragma unroll
                for (int tj = 0; tj < 2; ++tj)
                    acc[ti][tj] = __builtin_amdgcn_mfma_f32_32x32x16_bf16(a_h[ti], b_h[tj], acc[ti][tj], 0, 0, 0);
        }
        __syncthreads();
    }
#pragma unroll
    for (int ti = 0; ti < 2; ++ti)
#pragma unroll
        for (int tj = 0; tj < 2; ++tj)
#pragma unroll
            for (int r = 0; r < 16; ++r) {
                int row = bm + wt * 64 + ti * 32 + (r & 3) + 8 * (r >> 2) + 4 * hv;
                int col = bn + wn * 64 + tj * 32 + fm;
                Ph[(size_t)row * LDN + col] = f2bf(acc[ti][tj][r]);
            }
}

// ---------------- selector layers 2-3 + softmax + WP=w*prob (f16) ----------
__global__ void selector2(const u16* __restrict__ Ph,
                          const float* __restrict__ msd, const float* __restrict__ s1,
                          const float* __restrict__ b1, const float* __restrict__ w2,
                          const float* __restrict__ b2, const float* __restrict__ w3,
                          const float* __restrict__ b3, __half* __restrict__ WP) {
    __shared__ float h1s[4][64];
    __shared__ float h2s[4][64];
    __shared__ float lg[4][3];
    int tid = threadIdx.x;
    int slot = tid >> 6, j = tid & 63;
    int bt = blockIdx.x * 4 + slot;
    int b = bt >> 11, t = bt & 2047;
    size_t pidx = (size_t)bt * LDN + SELO + j;
    float v = bf2f(Ph[pidx])
            + msd[b * 64 + j] + 0.1f * ((float)t / (float)T_) * s1[j] + b1[j];
    h1s[slot][j] = fmaxf(v, 0.f);
    __syncthreads();
    float a2 = b2[j];
#pragma unroll 8
    for (int d = 0; d < 64; ++d) a2 = fmaf(h1s[slot][d], w2[j * 64 + d], a2);
    h2s[slot][j] = fmaxf(a2, 0.f);
    __syncthreads();
    if (j < 3) {
        float a3 = b3[j];
        for (int d = 0; d < 64; ++d) a3 = fmaf(h2s[slot][d], w3[j * 64 + d], a3);
        lg[slot][j] = a3;
    }
    __syncthreads();
    if (j < 28) {
        float m = fmaxf(lg[slot][0], fmaxf(lg[slot][1], lg[slot][2]));
        float e0 = expf(lg[slot][0] - m), e1 = expf(lg[slot][1] - m), e2 = expf(lg[slot][2] - m);
        float inv = 1.f / (e0 + e1 + e2);
        int wcol = (j < 4) ? (WO0 + j) : ((j < 12) ? (WO1 + j - 4) : (WO2 + j - 12));
        float p = ((j < 4) ? e0 : ((j < 12) ? e1 : e2)) * inv;
        float w = bf2f(Ph[(size_t)bt * LDN + wcol]);
        WP[(size_t)(b * 28 + j) * T_ + t] = __float2half(w * p);
    }
}

__device__ __forceinline__ int qcol_of(int c) {
    if (c < 2)  return QO0 + c * 64;
    if (c < 10) return QO1 + (c - 2) * 64;
    return QO2 + (c - 10) * 64;
}

// ---------------- fused relu-attention score kernel ----------------
// block 128x128, 4 waves 64x64, 42 x 64-col phases, constant-folded cfg sections
__global__ __launch_bounds__(256, 2) void score_kernel(
    const u16* __restrict__ Ph, const __half* __restrict__ WP, float* __restrict__ out) {
    __shared__ u16 Qs[2][8192];    // dbuf: 2 planes x [128][32]
    __shared__ u16 Ks[4 * 4096];   // up to 4 planes x [128][32]
    __shared__ __half wpL[3584];   // [28][128]
    int tid = threadIdx.x;
    int wave = tid >> 6, lane = tid & 63;
    int wt = wave >> 1, wn = wave & 1;
    int fm = lane & 31, hv = lane >> 5;
    int tkey = (fm & 3) ^ ((fm >> 2) & 3);

    // XCD-aware swizzle: blocks sharing a Q-tile land on one XCD
    int n = blockIdx.z * 256 + blockIdx.y * 16 + blockIdx.x;
    int p = (n & 7) * 4 + (n >> 7);
    int xb = (n >> 3) & 15;
    int b = p >> 4, yb = p & 15;
    int t0 = yb * 128, s0 = xb * 128;

    const u16* Pq = Ph + (size_t)(b * T_ + t0) * LDN;
    const u16* Pk = Ph + (size_t)(b * T_ + s0) * LDN;

    auto stageQ = [&](int buf, int qcol) {
#pragma unroll
        for (int i = 0; i < 4; ++i) {
            int j = (wave << 2) + i;
            int pl = j >> 3, rg = j & 7;
            stage_plane(Pq, LDN, qcol + pl * 32, rg, lane, &Qs[buf][pl * 4096]);
        }
    };

    // prologue: K planes 0 (KO0), 1 (KO1), 2 (KO1+32) — 3 planes x 8 row-groups = 24 jobs
#pragma unroll
    for (int i = 0; i < 6; ++i) {
        int j = i * 4 + wave;                  // 0..23
        int pl = j >> 3, rg = j & 7;
        int col = (pl == 0) ? KO0 : ((pl == 1) ? KO1 : KO1 + 32);
        stage_plane(Pk, LDN, col, rg, lane, &Ks[pl * 4096]);
    }
    // wp slice: 28 rows of 128 halfs, 7 gload jobs
#pragma unroll
    for (int i = 0; i < 2; ++i) {
        int j = i * 4 + wave;
        if (j < 7) {
            const __half* src = WP + (size_t)(b * 28 + j * 4 + (lane >> 4)) * T_ + t0 + (lane & 15) * 8;
            gload16(src, (u16*)wpL + j * 512);
        }
    }
    stageQ(0, QO0);

    f32x16 outacc[2][2], dots[2][2], Z16;
#pragma unroll
    for (int r = 0; r < 16; ++r) Z16[r] = 0.f;
#pragma unroll
    for (int i = 0; i < 2; ++i)
#pragma unroll
        for (int j = 0; j < 2; ++j)
#pragma unroll
            for (int r = 0; r < 16; ++r) { outacc[i][j][r] = 0.f; dots[i][j][r] = 0.f; }

    // relu-weight epilogue for head g (dots -> outacc)
    auto epi = [&](int g) {
#pragma unroll
        for (int ti = 0; ti < 2; ++ti) {
            int rowbase = wt * 64 + ti * 32 + 4 * hv;
#pragma unroll
            for (int rq = 0; rq < 4; ++rq) {
                const __half2* wp2 = (const __half2*)&wpL[g * 128 + rowbase + rq * 8];
                float2 f01 = __half22float2(wp2[0]);
                float2 f23 = __half22float2(wp2[1]);
                float wv[4] = {f01.x, f01.y, f23.x, f23.y};
#pragma unroll
                for (int tj = 0; tj < 2; ++tj)
#pragma unroll
                    for (int r2 = 0; r2 < 4; ++r2) {
                        int r = rq * 4 + r2;
                        outacc[ti][tj][r] += fmaxf(dots[ti][tj][r], 0.f) * wv[r2];
                    }
            }
        }
    };

    // one 64-col phase: 4 ks-steps; compile-time-constant control at call sites
    auto phase64 = [&](const u16* qb, int kpA, int kpB, bool z0, bool midBreak,
                       int gMid, bool hasEnd, int gEnd) {
#pragma unroll
        for (int ks = 0; ks < 4; ++ks) {
            int kp = (ks < 2) ? kpA : kpB;
            int slot8 = (((ks & 1) * 2 + hv) ^ tkey) * 8;
            bool zero = (ks == 0 && z0) || (ks == 2 && midBreak);
            bf16x8 kf[2], qf[2];
#pragma unroll
            for (int tj = 0; tj < 2; ++tj)
                kf[tj] = *(const bf16x8*)&Ks[kp * 4096 + (wn * 64 + tj * 32 + fm) * 32 + slot8];
#pragma unroll
            for (int ti = 0; ti < 2; ++ti)
                qf[ti] = *(const bf16x8*)&qb[(ks >> 1) * 4096 + (wt * 64 + ti * 32 + fm) * 32 + slot8];
#pragma unroll
            for (int ti = 0; ti < 2; ++ti)
#pragma unroll
                for (int tj = 0; tj < 2; ++tj)
                    dots[ti][tj] = __builtin_amdgcn_mfma_f32_32x32x16_bf16(
                        qf[ti], kf[tj], zero ? Z16 : dots[ti][tj], 0, 0, 0);
            if (ks == 1 && midBreak) epi(gMid);
            if (ks == 3 && hasEnd)   epi(gEnd);
        }
    };

    // cfg0: 2 phases, K plane 0, two d=32 heads per phase
#pragma unroll
    for (int c = 0; c < 2; ++c) {
        __syncthreads();
        stageQ((c + 1) & 1, qcol_of(c + 1));
        phase64(Qs[c & 1], 0, 0, true, true, 2 * c, true, 2 * c + 1);
    }
    // cfg1: 8 phases (one d=64 head each), K planes 1,2
    for (int h = 0; h < 8; ++h) {
        int c = 2 + h;
        __syncthreads();
        stageQ((c + 1) & 1, qcol_of(c + 1));
        phase64(Qs[c & 1], 1, 2, true, false, -1, true, 4 + h);
        if (h == 7) {
            __syncthreads();   // all waves done with cfg0/cfg1 K planes
            for (int j = wave; j < 32; j += 4) {
                int pl = j >> 3, rg = j & 7;
                stage_plane(Pk, LDN, KO2 + pl * 32, rg, lane, &Ks[pl * 4096]);
            }
        }
    }
    // cfg2: 16 heads x 2 phases (d=128), K planes 0..3
    for (int h = 0; h < 16; ++h) {
        int c = 10 + 2 * h;
        __syncthreads();
        stageQ((c + 1) & 1, qcol_of(c + 1));
        phase64(Qs[c & 1], 0, 1, true, false, -1, false, -1);
        __syncthreads();
        if (c + 1 < 41) stageQ(c & 1, qcol_of(c + 2));
        phase64(Qs[(c + 1) & 1], 2, 3, false, false, -1, true, 12 + h);
    }

#pragma unroll
    for (int ti = 0; ti < 2; ++ti)
#pragma unroll
        for (int tj = 0; tj < 2; ++tj)
#pragma unroll
            for (int r = 0; r < 16; ++r) {
                int trow = wt * 64 + ti * 32 + (r & 3) + 8 * (r >> 2) + 4 * hv;
                int scol = wn * 64 + tj * 32 + fm;
                out[(size_t)(b * T_ + t0 + trow) * T_ + (s0 + scol)] = outacc[ti][tj][r];
            }
}

extern "C" void kernel_launch(void* const* d_in, const int* in_sizes, int n_in,
                              void* d_out, int out_size, void* d_ws, size_t ws_size,
                              hipStream_t stream) {
    const float* x   = (const float*)d_in[0];
    const float* w1  = (const float*)d_in[1];
    const float* b1  = (const float*)d_in[2];
    const float* w2  = (const float*)d_in[3];
    const float* b2  = (const float*)d_in[4];
    const float* w3  = (const float*)d_in[5];
    const float* b3  = (const float*)d_in[6];
    const float* qw0 = (const float*)d_in[7];
    const float* kw0 = (const float*)d_in[8];
    const float* ww0 = (const float*)d_in[9];
    const float* qw1 = (const float*)d_in[10];
    const float* kw1 = (const float*)d_in[11];
    const float* ww1 = (const float*)d_in[12];
    const float* qw2 = (const float*)d_in[13];
    const float* kw2 = (const float*)d_in[14];
    const float* ww2 = (const float*)d_in[15];
    float* out = (float*)d_out;

    float* fb = (float*)d_ws;
    float* PA  = fb; fb += (size_t)B_ * 128 * D_;   // 1 MB
    float* PA2 = fb; fb += (size_t)B_ * 128 * D_;   // 1 MB
    float* MSD = fb; fb += 128;
    float* S1  = fb; fb += 64;
    __half* WP = (__half*)fb; fb += (size_t)B_ * 28 * T_ / 2;
    u16* ub = (u16*)fb;
    u16* Wh = ub; ub += (size_t)LDN * D_;      // 6.3 MB
    u16* Xh = ub; ub += (size_t)M_ * D_;       // 8 MB
    u16* Ph = ub; ub += (size_t)M_ * LDN;      // 25 MB

    stats1<<<dim3(D_ / 256, 128, B_), 256, 0, stream>>>(x, PA, PA2, Xh);
    stats2<<<dim3(B_), 1024, 0, stream>>>(PA, PA2, w1, MSD, S1);
    split_w<<<dim3(LDN), 256, 0, stream>>>(qw0, kw0, ww0, qw1, kw1, ww1,
                                           qw2, kw2, ww2, w1, Wh);
    proj_gemm<<<dim3(M_ / 128, LDN / 128), 256, 0, stream>>>(Xh, Wh, Ph);
    selector2<<<dim3(M_ / 4), 256, 0, stream>>>(Ph, MSD, S1, b1, w2, b2, w3, b3, WP);
    score_kernel<<<dim3(T_ / 128, T_ / 128, B_), 256, 0, stream>>>(Ph, WP, out);
}